// Round 2
// baseline (299.825 us; speedup 1.0000x reference)
//
#include <hip/hip_runtime.h>

typedef __bf16 bf16;
typedef __attribute__((ext_vector_type(8))) __bf16 bf16x8;
typedef __attribute__((ext_vector_type(4))) __bf16 bf16x4;
typedef __attribute__((ext_vector_type(4))) float f32x4;

static __device__ __forceinline__ f32x4 mfma16(bf16x8 a, bf16x8 b, f32x4 c) {
    return __builtin_amdgcn_mfma_f32_16x16x32_bf16(a, b, c, 0, 0, 0);
}

// async global->LDS, 16B per lane; lds base must be wave-uniform
static __device__ __forceinline__ void gll16(const bf16* g, bf16* l) {
    __builtin_amdgcn_global_load_lds(
        (const __attribute__((address_space(1))) unsigned int*)g,
        (__attribute__((address_space(3))) unsigned int*)l, 16, 0, 0);
}

// =====================================================================
// x fp32 -> bf16 (once; result aliased into the Apre workspace slot)
// =====================================================================
__global__ __launch_bounds__(256) void xcvt_kernel(
    const float* __restrict__ x, bf16* __restrict__ xb)
{
    size_t i = ((size_t)blockIdx.x * 256 + threadIdx.x) * 8;
    float4 a0 = *(const float4*)&x[i];
    float4 a1 = *(const float4*)&x[i + 4];
    bf16x8 v = {(bf16)a0.x, (bf16)a0.y, (bf16)a0.z, (bf16)a0.w,
                (bf16)a1.x, (bf16)a1.y, (bf16)a1.z, (bf16)a1.w};
    *(bf16x8*)&xb[i] = v;
}

// =====================================================================
// Weight transpose + convert: W[k][n] (1024x1024 fp32) -> WT[n][k] (bf16)
// =====================================================================
__global__ __launch_bounds__(256) void wtrans_kernel(
    const float* __restrict__ Wq, const float* __restrict__ Wk,
    const float* __restrict__ Wv, const float* __restrict__ Wo,
    bf16* __restrict__ WTqkv, bf16* __restrict__ WTo)
{
    __shared__ bf16 tile[64][65];
    const int bid = blockIdx.x;
    const int mi = bid >> 8;
    const int t  = bid & 255;
    const int tr = t >> 4;
    const int tc = t & 15;
    const int tid = threadIdx.x;

    const float* src = (mi == 0) ? Wq : (mi == 1) ? Wk : (mi == 2) ? Wv : Wo;
    bf16* dst = (mi < 3) ? (WTqkv + (size_t)mi * 1024 * 1024) : WTo;

    #pragma unroll
    for (int i = 0; i < 16; i++) {
        int idx = i * 256 + tid;
        int rl = idx >> 6, cl = idx & 63;
        tile[rl][cl] = (bf16)src[(size_t)(tr * 64 + rl) * 1024 + tc * 64 + cl];
    }
    __syncthreads();
    #pragma unroll
    for (int i = 0; i < 16; i++) {
        int idx = i * 256 + tid;
        int rl = idx >> 6, cl = idx & 63;
        dst[(size_t)(tc * 64 + rl) * 1024 + tr * 64 + cl] = tile[cl][rl];
    }
}

// bias concat (fp32): [b_q | b_k | b_v] -> 3072 floats
__global__ void biascat_kernel(const float* __restrict__ bq, const float* __restrict__ bk,
                               const float* __restrict__ bv, float* __restrict__ dst)
{
    int i = blockIdx.x * 256 + threadIdx.x;
    if (i < 1024) dst[i] = bq[i];
    else if (i < 2048) dst[i] = bk[i - 1024];
    else dst[i] = bv[i - 2048];
}

// =====================================================================
// m97-style GEMM: A bf16, BT bf16, global_load_lds(16B) staging.
// C = A @ BT^T + bias, bf16 out; cols<1024 scaled by QSCALE if scaleQ
// (folds 1/sqrt(d_k) * log2(e) into Q so softmax is a bare exp2).
// =====================================================================
#define QSCALE 0.18033688011112043f   // 0.125 * log2(e)
__global__ __launch_bounds__(256) void gemm_bf16_kernel(
    const bf16* __restrict__ A, const bf16* __restrict__ BT,
    const float* __restrict__ bias, bf16* __restrict__ C,
    int M, int N, int K, int scaleQ)
{
    __shared__ bf16 sA[128 * 32];
    __shared__ bf16 sB[128 * 32];
    const int tid  = threadIdx.x;
    const int lane = tid & 63;
    const int wave = tid >> 6;
    const int quad = lane >> 4;
    const int l15  = lane & 15;
    const int wm = (wave >> 1) * 64;
    const int wn = (wave & 1) * 64;
    const int m0 = blockIdx.y * 128;
    const int n0 = blockIdx.x * 128;

    const f32x4 fzero = {0.f, 0.f, 0.f, 0.f};
    f32x4 acc[4][4];
    #pragma unroll
    for (int i = 0; i < 4; i++)
        #pragma unroll
        for (int j = 0; j < 4; j++) acc[i][j] = fzero;

    float bv[4];
    #pragma unroll
    for (int nc = 0; nc < 4; nc++) bv[nc] = bias[n0 + wn + nc * 16 + l15];

    const int rA = lane >> 2;
    const int cA = (lane & 3) * 8;

    for (int k0 = 0; k0 < K; k0 += 32) {
        #pragma unroll
        for (int p = 0; p < 2; p++) {
            int r16 = (wave * 2 + p) * 16;
            gll16(&A[(size_t)(m0 + r16 + rA) * K + k0 + cA], &sA[r16 * 32]);
            gll16(&BT[(size_t)(n0 + r16 + rA) * K + k0 + cA], &sB[r16 * 32]);
        }
        __syncthreads();

        bf16x8 aF[4], bF[4];
        #pragma unroll
        for (int mc = 0; mc < 4; mc++)
            aF[mc] = *(const bf16x8*)&sA[(wm + mc * 16 + l15) * 32 + quad * 8];
        #pragma unroll
        for (int nc = 0; nc < 4; nc++)
            bF[nc] = *(const bf16x8*)&sB[(wn + nc * 16 + l15) * 32 + quad * 8];

        #pragma unroll
        for (int mc = 0; mc < 4; mc++)
            #pragma unroll
            for (int nc = 0; nc < 4; nc++)
                acc[mc][nc] = mfma16(aF[mc], bF[nc], acc[mc][nc]);
        __syncthreads();
    }

    const float sc = (scaleQ && n0 < 1024) ? QSCALE : 1.0f;
    #pragma unroll
    for (int mc = 0; mc < 4; mc++) {
        #pragma unroll
        for (int reg = 0; reg < 4; reg++) {
            int row = m0 + wm + mc * 16 + quad * 4 + reg;
            size_t base = (size_t)row * N + n0 + wn;
            #pragma unroll
            for (int nc = 0; nc < 4; nc++)
                C[base + nc * 16 + l15] = (bf16)((acc[mc][nc][reg] + bv[nc]) * sc);
        }
    }
}

// Same structure, fp32 output (final projection -> d_out)
__global__ __launch_bounds__(256) void gemm_bf16_f32out_kernel(
    const bf16* __restrict__ A, const bf16* __restrict__ BT,
    const float* __restrict__ bias, float* __restrict__ C,
    int M, int N, int K)
{
    __shared__ bf16 sA[128 * 32];
    __shared__ bf16 sB[128 * 32];
    const int tid  = threadIdx.x;
    const int lane = tid & 63;
    const int wave = tid >> 6;
    const int quad = lane >> 4;
    const int l15  = lane & 15;
    const int wm = (wave >> 1) * 64;
    const int wn = (wave & 1) * 64;
    const int m0 = blockIdx.y * 128;
    const int n0 = blockIdx.x * 128;

    const f32x4 fzero = {0.f, 0.f, 0.f, 0.f};
    f32x4 acc[4][4];
    #pragma unroll
    for (int i = 0; i < 4; i++)
        #pragma unroll
        for (int j = 0; j < 4; j++) acc[i][j] = fzero;

    float bv[4];
    #pragma unroll
    for (int nc = 0; nc < 4; nc++) bv[nc] = bias[n0 + wn + nc * 16 + l15];

    const int rA = lane >> 2;
    const int cA = (lane & 3) * 8;

    for (int k0 = 0; k0 < K; k0 += 32) {
        #pragma unroll
        for (int p = 0; p < 2; p++) {
            int r16 = (wave * 2 + p) * 16;
            gll16(&A[(size_t)(m0 + r16 + rA) * K + k0 + cA], &sA[r16 * 32]);
            gll16(&BT[(size_t)(n0 + r16 + rA) * K + k0 + cA], &sB[r16 * 32]);
        }
        __syncthreads();

        bf16x8 aF[4], bF[4];
        #pragma unroll
        for (int mc = 0; mc < 4; mc++)
            aF[mc] = *(const bf16x8*)&sA[(wm + mc * 16 + l15) * 32 + quad * 8];
        #pragma unroll
        for (int nc = 0; nc < 4; nc++)
            bF[nc] = *(const bf16x8*)&sB[(wn + nc * 16 + l15) * 32 + quad * 8];

        #pragma unroll
        for (int mc = 0; mc < 4; mc++)
            #pragma unroll
            for (int nc = 0; nc < 4; nc++)
                acc[mc][nc] = mfma16(aF[mc], bF[nc], acc[mc][nc]);
        __syncthreads();
    }

    #pragma unroll
    for (int mc = 0; mc < 4; mc++) {
        #pragma unroll
        for (int reg = 0; reg < 4; reg++) {
            int row = m0 + wm + mc * 16 + quad * 4 + reg;
            size_t base = (size_t)row * N + n0 + wn;
            #pragma unroll
            for (int nc = 0; nc < 4; nc++)
                C[base + nc * 16 + l15] = acc[mc][nc][reg] + bv[nc];
        }
    }
}

// =====================================================================
// V transpose: QKVp[b][n][2048 + h*64 + d] -> Vt[b*16+h][d][n]
// =====================================================================
__global__ __launch_bounds__(256) void vtrans_kernel(
    const bf16* __restrict__ QKVp, bf16* __restrict__ Vt)
{
    __shared__ bf16 tile[64][65];
    const int bid = blockIdx.x;
    const int bh = bid >> 5;
    const int nt = bid & 31;
    const int b = bh >> 4, h = bh & 15;
    const int tid = threadIdx.x;

    #pragma unroll
    for (int i = 0; i < 16; i++) {
        int idx = i * 256 + tid;
        int rl = idx >> 6, cl = idx & 63;
        tile[rl][cl] = QKVp[(size_t)(b * 2048 + nt * 64 + rl) * 3072 + 2048 + h * 64 + cl];
    }
    __syncthreads();
    #pragma unroll
    for (int i = 0; i < 16; i++) {
        int idx = i * 256 + tid;
        int rl = idx >> 6, cl = idx & 63;
        Vt[((size_t)bh * 64 + rl) * 2048 + nt * 64 + cl] = tile[cl][rl];
    }
}

// =====================================================================
// Flash attention, P-in-registers, 32 q-rows per wave (2 Q-groups).
// Round-1 changes:
//   - 2-tile-deep register prefetch (two named reg sets A/B, 2 tiles per
//     loop body, even tiles->buf0 / odd->buf1): the vmcnt wait at each
//     LDS commit now lands 1-2 full compute phases after issue.  [T14++]
//   - XCD-chunked bid swizzle: all 16 q-tile blocks of a head (and 8
//     heads = 4MB K/V = one L2) land on one XCD -> K/V loads become L2
//     hits, cutting both latency stall and HBM re-fetch.         [T1]
//   - psum via MFMA ones-row: row-sum of P moves to the matrix pipe
//     (4 MFMA/tile replace 32 VALU adds + the final shfl reduce).
// Math/layout unchanged:
//   S^T = K*Q^T ; P^T = exp2(S^T) packed in-register as PV B-operand
//   O^T = V^T*P ; key-row permute c: (m>>2)*8+(c&1)*4+(m&3)+32(c>>1)
//   Swizzle: phys_granule = logical ^ sw(row), sw(row)=(row&3)|(((row>>3)&1)<<2)
// =====================================================================
__global__ __launch_bounds__(256) void attn_kernel(
    const bf16* __restrict__ QKV, const bf16* __restrict__ Vt,
    bf16* __restrict__ Opre)
{
    __shared__ bf16 sK[2][64 * 64];      // [key][d], swizzled, double-buffered
    __shared__ bf16 sV[2][64 * 64];      // [d][key], swizzled, double-buffered

    const int tid  = threadIdx.x;
    const int lane = tid & 63;
    const int w    = tid >> 6;
    const int quad = lane >> 4;
    const int l15  = lane & 15;
    // XCD-chunked swizzle: grid=1024=8*128 (bijective). XCD x owns heads
    // x*8..x*8+7 -> 8 * 512KB K/V = 4MB = one XCD L2.
    const int bid = (blockIdx.x & 7) * 128 + (blockIdx.x >> 3);
    const int bh = bid >> 4;        // 0..63
    const int qt = bid & 15;
    const int b = bh >> 4, h = bh & 15;
    const int q0 = qt * 128;

    // Q fragments as B-operand [n=q][k=d], two 16-row groups (Q pre-scaled)
    bf16x8 qF[2][2];
    #pragma unroll
    for (int g = 0; g < 2; g++) {
        size_t qrow = (size_t)(b * 2048 + q0 + w * 32 + g * 16 + l15) * 3072 + h * 64;
        qF[g][0] = *(const bf16x8*)&QKV[qrow + quad * 8];
        qF[g][1] = *(const bf16x8*)&QKV[qrow + 32 + quad * 8];
    }

    const f32x4 fzero = {0.f, 0.f, 0.f, 0.f};
    const bf16 one = (bf16)1.0f;
    const bf16x8 ones = {one, one, one, one, one, one, one, one};
    f32x4 ps[2] = {fzero, fzero};     // psum accumulators (all regs identical)
    f32x4 o[2][4];
    #pragma unroll
    for (int g = 0; g < 2; g++)
        #pragma unroll
        for (int mt = 0; mt < 4; mt++) o[g][mt] = fzero;

    const int srow = tid >> 3, sseg = tid & 7;    // staging: 64 rows x 8 granules
    const size_t kbase = (size_t)(b * 2048) * 3072 + 1024 + h * 64;
    const size_t vbase = (size_t)bh * 64 * 2048;
    // swizzled granule for staging writes (p-independent: +32 rows only flips bit5)
    const int sgsw = sseg ^ ((srow & 3) | (((srow >> 3) & 1) << 2));

    // swizzle factors for compute reads (row-dependent parts are l15-only)
    const int swk = (l15 & 3) | (((l15 >> 2) & 1) << 2);  // for S^T K-rows
    const int swv = (l15 & 3) | (((l15 >> 3) & 1) << 2);  // for V rows mt*16+l15

    // two named in-flight reg sets (2-tile-deep prefetch)
    bf16x8 stAK[2], stAV[2], stBK[2], stBV[2];

#define ISSUE(RK, RV, KEY0)                                                       \
    _Pragma("unroll")                                                             \
    for (int p = 0; p < 2; p++) {                                                 \
        int row = srow + p * 32;                                                  \
        RK[p] = *(const bf16x8*)&QKV[kbase + (size_t)((KEY0) + row) * 3072 + sseg * 8]; \
        RV[p] = *(const bf16x8*)&Vt[vbase + (size_t)row * 2048 + (KEY0) + sseg * 8];    \
    }

#define COMMIT(RK, RV, BUF)                                                       \
    _Pragma("unroll")                                                             \
    for (int p = 0; p < 2; p++) {                                                 \
        int row = srow + p * 32;                                                  \
        *(bf16x8*)&sK[BUF][row * 64 + sgsw * 8] = RK[p];                          \
        *(bf16x8*)&sV[BUF][row * 64 + sgsw * 8] = RV[p];                          \
    }

    auto compute_tile = [&](const bf16* sKc, const bf16* sVc) {
        // S^T tiles c=0..3, keys permuted; K frags shared across both q-groups.
        bf16x8 pB[2][2];
        #pragma unroll
        for (int c = 0; c < 4; c++) {
            int kr = ((l15 >> 2) << 3) + ((c & 1) << 2) + (l15 & 3) + ((c >> 1) << 5);
            bf16x8 kA0 = *(const bf16x8*)&sKc[kr * 64 + ((quad ^ swk) * 8)];
            bf16x8 kA1 = *(const bf16x8*)&sKc[kr * 64 + (((4 + quad) ^ swk) * 8)];
            #pragma unroll
            for (int g = 0; g < 2; g++) {
                __builtin_amdgcn_s_setprio(1);
                f32x4 st = mfma16(kA0, qF[g][0], fzero);
                st = mfma16(kA1, qF[g][1], st);
                __builtin_amdgcn_s_setprio(0);
                #pragma unroll
                for (int r = 0; r < 4; r++) {
                    float p = __builtin_amdgcn_exp2f(st[r]);
                    pB[g][c >> 1][(c & 1) * 4 + r] = (bf16)p;
                }
            }
        }
        // psum on the matrix pipe: colsum over this tile's 64 keys
        // (permutation of keys inside pB is sum-invariant)
        __builtin_amdgcn_s_setprio(1);
        #pragma unroll
        for (int g = 0; g < 2; g++) {
            ps[g] = mfma16(ones, pB[g][0], ps[g]);
            ps[g] = mfma16(ones, pB[g][1], ps[g]);
        }
        __builtin_amdgcn_s_setprio(0);
        // O^T += V^T . P : V frags shared across both q-groups
        #pragma unroll
        for (int mt = 0; mt < 4; mt++) {
            int vr = mt * 16 + l15;
            bf16x8 vA0 = *(const bf16x8*)&sVc[vr * 64 + ((quad ^ swv) * 8)];
            bf16x8 vA1 = *(const bf16x8*)&sVc[vr * 64 + (((4 + quad) ^ swv) * 8)];
            __builtin_amdgcn_s_setprio(1);
            #pragma unroll
            for (int g = 0; g < 2; g++) {
                o[g][mt] = mfma16(vA0, pB[g][0], o[g][mt]);
                o[g][mt] = mfma16(vA1, pB[g][1], o[g][mt]);
            }
            __builtin_amdgcn_s_setprio(0);
        }
    };

    // ---- prologue: tile0 -> regsA -> buf0 committed; tile1 -> regsB in flight
    ISSUE(stAK, stAV, 0);
    ISSUE(stBK, stBV, 64);
    COMMIT(stAK, stAV, 0);
    __syncthreads();

    // ---- main loop: 2 tiles per body; even tiles live in buf0, odd in buf1.
    // Loads issued 2 tiles ahead; each COMMIT's vmcnt wait is covered by
    // at least one full compute phase.
    for (int t = 0; t < 30; t += 2) {
        ISSUE(stAK, stAV, (t + 2) * 64);
        __builtin_amdgcn_sched_barrier(0);   // pin loads above compute
        compute_tile(sK[0], sV[0]);          // tile t
        COMMIT(stBK, stBV, 1);               // tile t+1
        __syncthreads();

        ISSUE(stBK, stBV, (t + 3) * 64);
        __builtin_amdgcn_sched_barrier(0);
        compute_tile(sK[1], sV[1]);          // tile t+1
        COMMIT(stAK, stAV, 0);               // tile t+2
        __syncthreads();
    }
    // ---- epilogue: tiles 30 (buf0) and 31 (regsB -> buf1)
    compute_tile(sK[0], sV[0]);
    COMMIT(stBK, stBV, 1);
    __syncthreads();
    compute_tile(sK[1], sV[1]);

#undef ISSUE
#undef COMMIT

    // psum is complete per-lane (MFMA reduced over all keys); all ps regs equal
    #pragma unroll
    for (int g = 0; g < 2; g++) {
        float inv = 1.0f / ps[g][0];
        size_t obase = (size_t)(b * 2048 + q0 + w * 32 + g * 16 + l15) * 1024 + h * 64;
        #pragma unroll
        for (int mt = 0; mt < 4; mt++) {
            bf16x4 ov = {(bf16)(o[g][mt][0] * inv), (bf16)(o[g][mt][1] * inv),
                         (bf16)(o[g][mt][2] * inv), (bf16)(o[g][mt][3] * inv)};
            *(bf16x4*)&Opre[obase + mt * 16 + quad * 4] = ov;
        }
    }
}

// =====================================================================
extern "C" void kernel_launch(void* const* d_in, const int* in_sizes, int n_in,
                              void* d_out, int out_size, void* d_ws, size_t ws_size,
                              hipStream_t stream)
{
    const float* x  = (const float*)d_in[0];
    const float* Wq = (const float*)d_in[1];
    const float* bq = (const float*)d_in[2];
    const float* Wk = (const float*)d_in[3];
    const float* bk = (const float*)d_in[4];
    const float* Wv = (const float*)d_in[5];
    const float* bv = (const float*)d_in[6];
    const float* Wo = (const float*)d_in[7];
    const float* bo = (const float*)d_in[8];
    float* out = (float*)d_out;

    bf16* WTqkv = (bf16*)d_ws;                         // 3072*1024 bf16
    bf16* WTo   = WTqkv + (size_t)3072 * 1024;         // 1024*1024 bf16
    float* bcat = (float*)(WTo + (size_t)1024 * 1024); // 3072 f32 (pad 4096)
    bf16* QKVp  = (bf16*)(bcat + 4096);                // 8192*3072 bf16
    bf16* Vt    = QKVp + (size_t)8192 * 3072;          // 64*64*2048 bf16
    bf16* Apre  = Vt + (size_t)64 * 64 * 2048;         // 8192*1024 bf16
    bf16* xb    = Apre;   // alias: x-as-bf16 lives here until attn overwrites
    (void)ws_size; (void)n_in; (void)in_sizes; (void)out_size;

    xcvt_kernel<<<4096, 256, 0, stream>>>(x, xb);
    wtrans_kernel<<<1024, 256, 0, stream>>>(Wq, Wk, Wv, Wo, WTqkv, WTo);
    biascat_kernel<<<12, 256, 0, stream>>>(bq, bk, bv, bcat);
    gemm_bf16_kernel<<<dim3(24, 64), 256, 0, stream>>>(xb, WTqkv, bcat, QKVp, 8192, 3072, 1024, 1);
    vtrans_kernel<<<2048, 256, 0, stream>>>(QKVp, Vt);
    attn_kernel<<<1024, 256, 0, stream>>>(QKVp, Vt, Apre);
    gemm_bf16_f32out_kernel<<<dim3(8, 64), 256, 0, stream>>>(Apre, WTo, bo, out, 8192, 1024, 1024);
}

// Round 3
// 286.737 us; speedup vs baseline: 1.0456x; 1.0456x over previous
//
#include <hip/hip_runtime.h>

typedef __bf16 bf16;
typedef __attribute__((ext_vector_type(8))) __bf16 bf16x8;
typedef __attribute__((ext_vector_type(4))) __bf16 bf16x4;
typedef __attribute__((ext_vector_type(4))) float f32x4;

static __device__ __forceinline__ f32x4 mfma16(bf16x8 a, bf16x8 b, f32x4 c) {
    return __builtin_amdgcn_mfma_f32_16x16x32_bf16(a, b, c, 0, 0, 0);
}

// async global->LDS, 16B per lane; lds base must be wave-uniform
static __device__ __forceinline__ void gll16(const bf16* g, bf16* l) {
    __builtin_amdgcn_global_load_lds(
        (const __attribute__((address_space(1))) unsigned int*)g,
        (__attribute__((address_space(3))) unsigned int*)l, 16, 0, 0);
}

// =====================================================================
// x fp32 -> bf16 (once; result aliased into the Apre workspace slot)
// =====================================================================
__global__ __launch_bounds__(256) void xcvt_kernel(
    const float* __restrict__ x, bf16* __restrict__ xb)
{
    size_t i = ((size_t)blockIdx.x * 256 + threadIdx.x) * 8;
    float4 a0 = *(const float4*)&x[i];
    float4 a1 = *(const float4*)&x[i + 4];
    bf16x8 v = {(bf16)a0.x, (bf16)a0.y, (bf16)a0.z, (bf16)a0.w,
                (bf16)a1.x, (bf16)a1.y, (bf16)a1.z, (bf16)a1.w};
    *(bf16x8*)&xb[i] = v;
}

// =====================================================================
// Weight transpose + convert: W[k][n] (1024x1024 fp32) -> WT[n][k] (bf16)
// =====================================================================
__global__ __launch_bounds__(256) void wtrans_kernel(
    const float* __restrict__ Wq, const float* __restrict__ Wk,
    const float* __restrict__ Wv, const float* __restrict__ Wo,
    bf16* __restrict__ WTqkv, bf16* __restrict__ WTo)
{
    __shared__ bf16 tile[64][65];
    const int bid = blockIdx.x;
    const int mi = bid >> 8;
    const int t  = bid & 255;
    const int tr = t >> 4;
    const int tc = t & 15;
    const int tid = threadIdx.x;

    const float* src = (mi == 0) ? Wq : (mi == 1) ? Wk : (mi == 2) ? Wv : Wo;
    bf16* dst = (mi < 3) ? (WTqkv + (size_t)mi * 1024 * 1024) : WTo;

    #pragma unroll
    for (int i = 0; i < 16; i++) {
        int idx = i * 256 + tid;
        int rl = idx >> 6, cl = idx & 63;
        tile[rl][cl] = (bf16)src[(size_t)(tr * 64 + rl) * 1024 + tc * 64 + cl];
    }
    __syncthreads();
    #pragma unroll
    for (int i = 0; i < 16; i++) {
        int idx = i * 256 + tid;
        int rl = idx >> 6, cl = idx & 63;
        dst[(size_t)(tc * 64 + rl) * 1024 + tr * 64 + cl] = tile[cl][rl];
    }
}

// bias concat (fp32): [b_q | b_k | b_v] -> 3072 floats
__global__ void biascat_kernel(const float* __restrict__ bq, const float* __restrict__ bk,
                               const float* __restrict__ bv, float* __restrict__ dst)
{
    int i = blockIdx.x * 256 + threadIdx.x;
    if (i < 1024) dst[i] = bq[i];
    else if (i < 2048) dst[i] = bk[i - 1024];
    else dst[i] = bv[i - 2048];
}

// =====================================================================
// m97-style GEMM: A bf16, BT bf16, global_load_lds(16B) staging.
// C = A @ BT^T + bias, bf16 out; cols<1024 scaled by QSCALE if scaleQ
// (folds 1/sqrt(d_k) * log2(e) into Q so softmax is a bare exp2).
// =====================================================================
#define QSCALE 0.18033688011112043f   // 0.125 * log2(e)
__global__ __launch_bounds__(256) void gemm_bf16_kernel(
    const bf16* __restrict__ A, const bf16* __restrict__ BT,
    const float* __restrict__ bias, bf16* __restrict__ C,
    int M, int N, int K, int scaleQ)
{
    __shared__ bf16 sA[128 * 32];
    __shared__ bf16 sB[128 * 32];
    const int tid  = threadIdx.x;
    const int lane = tid & 63;
    const int wave = tid >> 6;
    const int quad = lane >> 4;
    const int l15  = lane & 15;
    const int wm = (wave >> 1) * 64;
    const int wn = (wave & 1) * 64;
    const int m0 = blockIdx.y * 128;
    const int n0 = blockIdx.x * 128;

    const f32x4 fzero = {0.f, 0.f, 0.f, 0.f};
    f32x4 acc[4][4];
    #pragma unroll
    for (int i = 0; i < 4; i++)
        #pragma unroll
        for (int j = 0; j < 4; j++) acc[i][j] = fzero;

    float bv[4];
    #pragma unroll
    for (int nc = 0; nc < 4; nc++) bv[nc] = bias[n0 + wn + nc * 16 + l15];

    const int rA = lane >> 2;
    const int cA = (lane & 3) * 8;

    for (int k0 = 0; k0 < K; k0 += 32) {
        #pragma unroll
        for (int p = 0; p < 2; p++) {
            int r16 = (wave * 2 + p) * 16;
            gll16(&A[(size_t)(m0 + r16 + rA) * K + k0 + cA], &sA[r16 * 32]);
            gll16(&BT[(size_t)(n0 + r16 + rA) * K + k0 + cA], &sB[r16 * 32]);
        }
        __syncthreads();

        bf16x8 aF[4], bF[4];
        #pragma unroll
        for (int mc = 0; mc < 4; mc++)
            aF[mc] = *(const bf16x8*)&sA[(wm + mc * 16 + l15) * 32 + quad * 8];
        #pragma unroll
        for (int nc = 0; nc < 4; nc++)
            bF[nc] = *(const bf16x8*)&sB[(wn + nc * 16 + l15) * 32 + quad * 8];

        #pragma unroll
        for (int mc = 0; mc < 4; mc++)
            #pragma unroll
            for (int nc = 0; nc < 4; nc++)
                acc[mc][nc] = mfma16(aF[mc], bF[nc], acc[mc][nc]);
        __syncthreads();
    }

    const float sc = (scaleQ && n0 < 1024) ? QSCALE : 1.0f;
    #pragma unroll
    for (int mc = 0; mc < 4; mc++) {
        #pragma unroll
        for (int reg = 0; reg < 4; reg++) {
            int row = m0 + wm + mc * 16 + quad * 4 + reg;
            size_t base = (size_t)row * N + n0 + wn;
            #pragma unroll
            for (int nc = 0; nc < 4; nc++)
                C[base + nc * 16 + l15] = (bf16)((acc[mc][nc][reg] + bv[nc]) * sc);
        }
    }
}

// Same structure, fp32 output (final projection -> d_out)
__global__ __launch_bounds__(256) void gemm_bf16_f32out_kernel(
    const bf16* __restrict__ A, const bf16* __restrict__ BT,
    const float* __restrict__ bias, float* __restrict__ C,
    int M, int N, int K)
{
    __shared__ bf16 sA[128 * 32];
    __shared__ bf16 sB[128 * 32];
    const int tid  = threadIdx.x;
    const int lane = tid & 63;
    const int wave = tid >> 6;
    const int quad = lane >> 4;
    const int l15  = lane & 15;
    const int wm = (wave >> 1) * 64;
    const int wn = (wave & 1) * 64;
    const int m0 = blockIdx.y * 128;
    const int n0 = blockIdx.x * 128;

    const f32x4 fzero = {0.f, 0.f, 0.f, 0.f};
    f32x4 acc[4][4];
    #pragma unroll
    for (int i = 0; i < 4; i++)
        #pragma unroll
        for (int j = 0; j < 4; j++) acc[i][j] = fzero;

    float bv[4];
    #pragma unroll
    for (int nc = 0; nc < 4; nc++) bv[nc] = bias[n0 + wn + nc * 16 + l15];

    const int rA = lane >> 2;
    const int cA = (lane & 3) * 8;

    for (int k0 = 0; k0 < K; k0 += 32) {
        #pragma unroll
        for (int p = 0; p < 2; p++) {
            int r16 = (wave * 2 + p) * 16;
            gll16(&A[(size_t)(m0 + r16 + rA) * K + k0 + cA], &sA[r16 * 32]);
            gll16(&BT[(size_t)(n0 + r16 + rA) * K + k0 + cA], &sB[r16 * 32]);
        }
        __syncthreads();

        bf16x8 aF[4], bF[4];
        #pragma unroll
        for (int mc = 0; mc < 4; mc++)
            aF[mc] = *(const bf16x8*)&sA[(wm + mc * 16 + l15) * 32 + quad * 8];
        #pragma unroll
        for (int nc = 0; nc < 4; nc++)
            bF[nc] = *(const bf16x8*)&sB[(wn + nc * 16 + l15) * 32 + quad * 8];

        #pragma unroll
        for (int mc = 0; mc < 4; mc++)
            #pragma unroll
            for (int nc = 0; nc < 4; nc++)
                acc[mc][nc] = mfma16(aF[mc], bF[nc], acc[mc][nc]);
        __syncthreads();
    }

    #pragma unroll
    for (int mc = 0; mc < 4; mc++) {
        #pragma unroll
        for (int reg = 0; reg < 4; reg++) {
            int row = m0 + wm + mc * 16 + quad * 4 + reg;
            size_t base = (size_t)row * N + n0 + wn;
            #pragma unroll
            for (int nc = 0; nc < 4; nc++)
                C[base + nc * 16 + l15] = acc[mc][nc][reg] + bv[nc];
        }
    }
}

// =====================================================================
// V transpose: QKVp[b][n][2048 + h*64 + d] -> Vt[b*16+h][d][n]
// =====================================================================
__global__ __launch_bounds__(256) void vtrans_kernel(
    const bf16* __restrict__ QKVp, bf16* __restrict__ Vt)
{
    __shared__ bf16 tile[64][65];
    const int bid = blockIdx.x;
    const int bh = bid >> 5;
    const int nt = bid & 31;
    const int b = bh >> 4, h = bh & 15;
    const int tid = threadIdx.x;

    #pragma unroll
    for (int i = 0; i < 16; i++) {
        int idx = i * 256 + tid;
        int rl = idx >> 6, cl = idx & 63;
        tile[rl][cl] = QKVp[(size_t)(b * 2048 + nt * 64 + rl) * 3072 + 2048 + h * 64 + cl];
    }
    __syncthreads();
    #pragma unroll
    for (int i = 0; i < 16; i++) {
        int idx = i * 256 + tid;
        int rl = idx >> 6, cl = idx & 63;
        Vt[((size_t)bh * 64 + rl) * 2048 + nt * 64 + cl] = tile[cl][rl];
    }
}

// =====================================================================
// Flash attention, P-in-registers, 64 q-rows per wave (4 Q-groups).
// Round-2 change: R2 proved the kernel is NOT BW-bound (FETCH dropped
// 5.6x, time unchanged).  Estimated LDS pipe ~51% busy: all waves read
// the SAME K/V fragments.  Doubling q-rows per wave (32->64) halves LDS
// reads + staging work per FLOP.  Block = 128 threads (2 waves x 64q),
// grid stays 1024 with the same XCD-chunked swizzle (K/V L2-resident).
// Prefetch back to 1-deep (L2 latency ~200-400cyc is covered by one
// compute phase; saves 32 VGPR).
// Math/layout unchanged:
//   S^T = K*Q^T ; P^T = exp2(S^T) packed in-register as PV B-operand
//   O^T = V^T*P ; key-row permute c: (m>>2)*8+(c&1)*4+(m&3)+32(c>>1)
//   Swizzle: phys_granule = logical ^ sw(row), sw(row)=(row&3)|(((row>>3)&1)<<2)
//   psum via MFMA ones-row (row-sum on the matrix pipe).
// =====================================================================
__global__ __launch_bounds__(128, 2) void attn_kernel(
    const bf16* __restrict__ QKV, const bf16* __restrict__ Vt,
    bf16* __restrict__ Opre)
{
    __shared__ bf16 sK[2][64 * 64];      // [key][d], swizzled, double-buffered
    __shared__ bf16 sV[2][64 * 64];      // [d][key], swizzled, double-buffered

    const int tid  = threadIdx.x;
    const int lane = tid & 63;
    const int w    = tid >> 6;            // 0..1
    const int quad = lane >> 4;
    const int l15  = lane & 15;
    // XCD-chunked swizzle: grid=1024=8*128 (bijective). XCD x owns heads
    // x*8..x*8+7 -> 8 * 512KB K/V = 4MB = one XCD L2.
    const int bid = (blockIdx.x & 7) * 128 + (blockIdx.x >> 3);
    const int bh = bid >> 4;        // 0..63
    const int qt = bid & 15;
    const int b = bh >> 4, h = bh & 15;
    const int q0 = qt * 128;

    // Q fragments as B-operand [n=q][k=d], four 16-row groups (Q pre-scaled)
    bf16x8 qF[4][2];
    #pragma unroll
    for (int g = 0; g < 4; g++) {
        size_t qrow = (size_t)(b * 2048 + q0 + w * 64 + g * 16 + l15) * 3072 + h * 64;
        qF[g][0] = *(const bf16x8*)&QKV[qrow + quad * 8];
        qF[g][1] = *(const bf16x8*)&QKV[qrow + 32 + quad * 8];
    }

    const f32x4 fzero = {0.f, 0.f, 0.f, 0.f};
    const bf16 one = (bf16)1.0f;
    const bf16x8 ones = {one, one, one, one, one, one, one, one};
    f32x4 ps[4] = {fzero, fzero, fzero, fzero};
    f32x4 o[4][4];
    #pragma unroll
    for (int g = 0; g < 4; g++)
        #pragma unroll
        for (int mt = 0; mt < 4; mt++) o[g][mt] = fzero;

    // staging: 128 threads, 64 rows x 8 granules, 4 rows/thread (stride 16)
    const int srow = tid >> 3, sseg = tid & 7;
    const size_t kbase = (size_t)(b * 2048) * 3072 + 1024 + h * 64;
    const size_t vbase = (size_t)bh * 64 * 2048;
    // swizzled granule for staging writes (p-invariant: +16 rows keeps
    // row&3 and (row>>3)&1 unchanged)
    const int sgsw = sseg ^ ((srow & 3) | (((srow >> 3) & 1) << 2));

    // swizzle factors for compute reads (row-dependent parts are l15-only)
    const int swk = (l15 & 3) | (((l15 >> 2) & 1) << 2);  // for S^T K-rows
    const int swv = (l15 & 3) | (((l15 >> 3) & 1) << 2);  // for V rows mt*16+l15

    bf16x8 stK[4], stV[4];    // in-flight staging regs (next tile)

#define ISSUE(KEY0)                                                               \
    _Pragma("unroll")                                                             \
    for (int p = 0; p < 4; p++) {                                                 \
        int row = srow + p * 16;                                                  \
        stK[p] = *(const bf16x8*)&QKV[kbase + (size_t)((KEY0) + row) * 3072 + sseg * 8]; \
        stV[p] = *(const bf16x8*)&Vt[vbase + (size_t)row * 2048 + (KEY0) + sseg * 8];    \
    }

#define COMMIT(BUF)                                                               \
    _Pragma("unroll")                                                             \
    for (int p = 0; p < 4; p++) {                                                 \
        int row = srow + p * 16;                                                  \
        *(bf16x8*)&sK[BUF][row * 64 + sgsw * 8] = stK[p];                         \
        *(bf16x8*)&sV[BUF][row * 64 + sgsw * 8] = stV[p];                         \
    }

    auto compute_tile = [&](const bf16* sKc, const bf16* sVc) {
        // S^T tiles c=0..3, keys permuted; K frags shared across all 4 q-groups.
        bf16x8 pB[4][2];
        #pragma unroll
        for (int c = 0; c < 4; c++) {
            int kr = ((l15 >> 2) << 3) + ((c & 1) << 2) + (l15 & 3) + ((c >> 1) << 5);
            bf16x8 kA0 = *(const bf16x8*)&sKc[kr * 64 + ((quad ^ swk) * 8)];
            bf16x8 kA1 = *(const bf16x8*)&sKc[kr * 64 + (((4 + quad) ^ swk) * 8)];
            #pragma unroll
            for (int g = 0; g < 4; g++) {
                __builtin_amdgcn_s_setprio(1);
                f32x4 st = mfma16(kA0, qF[g][0], fzero);
                st = mfma16(kA1, qF[g][1], st);
                __builtin_amdgcn_s_setprio(0);
                #pragma unroll
                for (int r = 0; r < 4; r++) {
                    float p = __builtin_amdgcn_exp2f(st[r]);
                    pB[g][c >> 1][(c & 1) * 4 + r] = (bf16)p;
                }
            }
        }
        // psum on the matrix pipe: colsum over this tile's 64 keys
        __builtin_amdgcn_s_setprio(1);
        #pragma unroll
        for (int g = 0; g < 4; g++) {
            ps[g] = mfma16(ones, pB[g][0], ps[g]);
            ps[g] = mfma16(ones, pB[g][1], ps[g]);
        }
        __builtin_amdgcn_s_setprio(0);
        // O^T += V^T . P : V frags shared across all 4 q-groups
        #pragma unroll
        for (int mt = 0; mt < 4; mt++) {
            int vr = mt * 16 + l15;
            bf16x8 vA0 = *(const bf16x8*)&sVc[vr * 64 + ((quad ^ swv) * 8)];
            bf16x8 vA1 = *(const bf16x8*)&sVc[vr * 64 + (((4 + quad) ^ swv) * 8)];
            __builtin_amdgcn_s_setprio(1);
            #pragma unroll
            for (int g = 0; g < 4; g++) {
                o[g][mt] = mfma16(vA0, pB[g][0], o[g][mt]);
                o[g][mt] = mfma16(vA1, pB[g][1], o[g][mt]);
            }
            __builtin_amdgcn_s_setprio(0);
        }
    };

    // ---- prologue: stage tile 0 into buffer 0 ----
    ISSUE(0);
    COMMIT(0);
    __syncthreads();

    // ---- main loop: issue t+1 early, compute t, commit t+1, barrier ----
    for (int t = 0; t < 31; t++) {
        ISSUE((t + 1) * 64);
        __builtin_amdgcn_sched_barrier(0);   // pin loads above compute
        compute_tile(sK[t & 1], sV[t & 1]);
        COMMIT((t + 1) & 1);                 // vmcnt wait covered by compute
        __syncthreads();
    }
    compute_tile(sK[1], sV[1]);              // tile 31 (odd -> buf1)

#undef ISSUE
#undef COMMIT

    // psum is complete per-lane (MFMA reduced over all keys); all ps regs equal
    #pragma unroll
    for (int g = 0; g < 4; g++) {
        float inv = 1.0f / ps[g][0];
        size_t obase = (size_t)(b * 2048 + q0 + w * 64 + g * 16 + l15) * 1024 + h * 64;
        #pragma unroll
        for (int mt = 0; mt < 4; mt++) {
            bf16x4 ov = {(bf16)(o[g][mt][0] * inv), (bf16)(o[g][mt][1] * inv),
                         (bf16)(o[g][mt][2] * inv), (bf16)(o[g][mt][3] * inv)};
            *(bf16x4*)&Opre[obase + mt * 16 + quad * 4] = ov;
        }
    }
}

// =====================================================================
extern "C" void kernel_launch(void* const* d_in, const int* in_sizes, int n_in,
                              void* d_out, int out_size, void* d_ws, size_t ws_size,
                              hipStream_t stream)
{
    const float* x  = (const float*)d_in[0];
    const float* Wq = (const float*)d_in[1];
    const float* bq = (const float*)d_in[2];
    const float* Wk = (const float*)d_in[3];
    const float* bk = (const float*)d_in[4];
    const float* Wv = (const float*)d_in[5];
    const float* bv = (const float*)d_in[6];
    const float* Wo = (const float*)d_in[7];
    const float* bo = (const float*)d_in[8];
    float* out = (float*)d_out;

    bf16* WTqkv = (bf16*)d_ws;                         // 3072*1024 bf16
    bf16* WTo   = WTqkv + (size_t)3072 * 1024;         // 1024*1024 bf16
    float* bcat = (float*)(WTo + (size_t)1024 * 1024); // 3072 f32 (pad 4096)
    bf16* QKVp  = (bf16*)(bcat + 4096);                // 8192*3072 bf16
    bf16* Vt    = QKVp + (size_t)8192 * 3072;          // 64*64*2048 bf16
    bf16* Apre  = Vt + (size_t)64 * 64 * 2048;         // 8192*1024 bf16
    bf16* xb    = Apre;   // alias: x-as-bf16 lives here until attn overwrites
    (void)ws_size; (void)n_in; (void)in_sizes; (void)out_size;

    xcvt_kernel<<<4096, 256, 0, stream>>>(x, xb);
    wtrans_kernel<<<1024, 256, 0, stream>>>(Wq, Wk, Wv, Wo, WTqkv, WTo);
    biascat_kernel<<<12, 256, 0, stream>>>(bq, bk, bv, bcat);
    gemm_bf16_kernel<<<dim3(24, 64), 256, 0, stream>>>(xb, WTqkv, bcat, QKVp, 8192, 3072, 1024, 1);
    vtrans_kernel<<<2048, 256, 0, stream>>>(QKVp, Vt);
    attn_kernel<<<1024, 128, 0, stream>>>(QKVp, Vt, Apre);
    gemm_bf16_f32out_kernel<<<dim3(8, 64), 256, 0, stream>>>(Apre, WTo, bo, out, 8192, 1024, 1024);
}

// Round 4
// 277.139 us; speedup vs baseline: 1.0819x; 1.0346x over previous
//
#include <hip/hip_runtime.h>

typedef __bf16 bf16;
typedef __attribute__((ext_vector_type(8))) __bf16 bf16x8;
typedef __attribute__((ext_vector_type(4))) __bf16 bf16x4;
typedef __attribute__((ext_vector_type(4))) float f32x4;

static __device__ __forceinline__ f32x4 mfma16(bf16x8 a, bf16x8 b, f32x4 c) {
    return __builtin_amdgcn_mfma_f32_16x16x32_bf16(a, b, c, 0, 0, 0);
}

// async global->LDS, 16B per lane; lds base must be wave-uniform
static __device__ __forceinline__ void gll16(const bf16* g, bf16* l) {
    __builtin_amdgcn_global_load_lds(
        (const __attribute__((address_space(1))) unsigned int*)g,
        (__attribute__((address_space(3))) unsigned int*)l, 16, 0, 0);
}

// =====================================================================
// x fp32 -> bf16 (once; result aliased into the Apre workspace slot)
// =====================================================================
__global__ __launch_bounds__(256) void xcvt_kernel(
    const float* __restrict__ x, bf16* __restrict__ xb)
{
    size_t i = ((size_t)blockIdx.x * 256 + threadIdx.x) * 8;
    float4 a0 = *(const float4*)&x[i];
    float4 a1 = *(const float4*)&x[i + 4];
    bf16x8 v = {(bf16)a0.x, (bf16)a0.y, (bf16)a0.z, (bf16)a0.w,
                (bf16)a1.x, (bf16)a1.y, (bf16)a1.z, (bf16)a1.w};
    *(bf16x8*)&xb[i] = v;
}

// =====================================================================
// Weight transpose + convert: W[k][n] (1024x1024 fp32) -> WT[n][k] (bf16)
// =====================================================================
__global__ __launch_bounds__(256) void wtrans_kernel(
    const float* __restrict__ Wq, const float* __restrict__ Wk,
    const float* __restrict__ Wv, const float* __restrict__ Wo,
    bf16* __restrict__ WTqkv, bf16* __restrict__ WTo)
{
    __shared__ bf16 tile[64][65];
    const int bid = blockIdx.x;
    const int mi = bid >> 8;
    const int t  = bid & 255;
    const int tr = t >> 4;
    const int tc = t & 15;
    const int tid = threadIdx.x;

    const float* src = (mi == 0) ? Wq : (mi == 1) ? Wk : (mi == 2) ? Wv : Wo;
    bf16* dst = (mi < 3) ? (WTqkv + (size_t)mi * 1024 * 1024) : WTo;

    #pragma unroll
    for (int i = 0; i < 16; i++) {
        int idx = i * 256 + tid;
        int rl = idx >> 6, cl = idx & 63;
        tile[rl][cl] = (bf16)src[(size_t)(tr * 64 + rl) * 1024 + tc * 64 + cl];
    }
    __syncthreads();
    #pragma unroll
    for (int i = 0; i < 16; i++) {
        int idx = i * 256 + tid;
        int rl = idx >> 6, cl = idx & 63;
        dst[(size_t)(tc * 64 + rl) * 1024 + tr * 64 + cl] = tile[cl][rl];
    }
}

// bias concat (fp32): [b_q | b_k | b_v] -> 3072 floats
__global__ void biascat_kernel(const float* __restrict__ bq, const float* __restrict__ bk,
                               const float* __restrict__ bv, float* __restrict__ dst)
{
    int i = blockIdx.x * 256 + threadIdx.x;
    if (i < 1024) dst[i] = bq[i];
    else if (i < 2048) dst[i] = bk[i - 1024];
    else dst[i] = bv[i - 2048];
}

// =====================================================================
// m97-style GEMM + Round-3 upgrades:
//  - T2 swizzle: LDS granule phys = logical ^ ((row>>1)&3).  Collapses to
//    thread-constant forms: staging source col ((lane&3)^((lane>>3)&3))*8
//    (LDS dest stays linear for global_load_lds; source pre-swizzled),
//    fragment read granule quad^((l15>>1)&3).  Kills the ~4-way
//    ds_read_b128 bank conflict (6.29M conflict cycles/dispatch).
//  - T3-min 2-phase: LDS double-buffered; tile t+1's gll16 issued BEFORE
//    tile t's compute, so the barrier's vmcnt drain lands a full compute
//    phase after issue.
// C = A @ BT^T + bias, bf16 out; cols<1024 scaled by QSCALE if scaleQ.
// =====================================================================
#define QSCALE 0.18033688011112043f   // 0.125 * log2(e)
__global__ __launch_bounds__(256) void gemm_bf16_kernel(
    const bf16* __restrict__ A, const bf16* __restrict__ BT,
    const float* __restrict__ bias, bf16* __restrict__ C,
    int M, int N, int K, int scaleQ)
{
    __shared__ bf16 sA[2][128 * 32];
    __shared__ bf16 sB[2][128 * 32];
    const int tid  = threadIdx.x;
    const int lane = tid & 63;
    const int wave = tid >> 6;
    const int quad = lane >> 4;
    const int l15  = lane & 15;
    const int wm = (wave >> 1) * 64;
    const int wn = (wave & 1) * 64;
    const int m0 = blockIdx.y * 128;
    const int n0 = blockIdx.x * 128;

    const f32x4 fzero = {0.f, 0.f, 0.f, 0.f};
    f32x4 acc[4][4];
    #pragma unroll
    for (int i = 0; i < 4; i++)
        #pragma unroll
        for (int j = 0; j < 4; j++) acc[i][j] = fzero;

    float bv[4];
    #pragma unroll
    for (int nc = 0; nc < 4; nc++) bv[nc] = bias[n0 + wn + nc * 16 + l15];

    const int rA = lane >> 2;
    const int cAsw = ((lane & 3) ^ ((lane >> 3) & 3)) * 8;   // pre-swizzled src col
    const int gsw = (l15 >> 1) & 3;                          // read granule swizzle

#define GSTAGE(K0, BUF)                                                           \
    _Pragma("unroll")                                                             \
    for (int p = 0; p < 2; p++) {                                                 \
        int r16 = (wave * 2 + p) * 16;                                            \
        gll16(&A[(size_t)(m0 + r16 + rA) * K + (K0) + cAsw], &sA[BUF][r16 * 32]); \
        gll16(&BT[(size_t)(n0 + r16 + rA) * K + (K0) + cAsw], &sB[BUF][r16 * 32]);\
    }

#define GCOMPUTE(BUF)                                                             \
    {                                                                             \
        bf16x8 aF[4], bF[4];                                                      \
        _Pragma("unroll")                                                         \
        for (int mc = 0; mc < 4; mc++)                                            \
            aF[mc] = *(const bf16x8*)&sA[BUF][(wm + mc * 16 + l15) * 32 + ((quad ^ gsw) * 8)]; \
        _Pragma("unroll")                                                         \
        for (int nc = 0; nc < 4; nc++)                                            \
            bF[nc] = *(const bf16x8*)&sB[BUF][(wn + nc * 16 + l15) * 32 + ((quad ^ gsw) * 8)]; \
        _Pragma("unroll")                                                         \
        for (int mc = 0; mc < 4; mc++)                                            \
            _Pragma("unroll")                                                     \
            for (int nc = 0; nc < 4; nc++)                                        \
                acc[mc][nc] = mfma16(aF[mc], bF[nc], acc[mc][nc]);                \
    }

    GSTAGE(0, 0);
    __syncthreads();
    int buf = 0;
    for (int k0 = 0; k0 < K - 32; k0 += 32, buf ^= 1) {
        GSTAGE(k0 + 32, buf ^ 1);
        __builtin_amdgcn_sched_barrier(0);   // keep stage issue above compute
        GCOMPUTE(buf);
        __syncthreads();                     // vmcnt drain: one phase after issue
    }
    GCOMPUTE(buf);                           // last tile

    const float sc = (scaleQ && n0 < 1024) ? QSCALE : 1.0f;
    #pragma unroll
    for (int mc = 0; mc < 4; mc++) {
        #pragma unroll
        for (int reg = 0; reg < 4; reg++) {
            int row = m0 + wm + mc * 16 + quad * 4 + reg;
            size_t base = (size_t)row * N + n0 + wn;
            #pragma unroll
            for (int nc = 0; nc < 4; nc++)
                C[base + nc * 16 + l15] = (bf16)((acc[mc][nc][reg] + bv[nc]) * sc);
        }
    }
}

// Same structure, fp32 output (final projection -> d_out)
__global__ __launch_bounds__(256) void gemm_bf16_f32out_kernel(
    const bf16* __restrict__ A, const bf16* __restrict__ BT,
    const float* __restrict__ bias, float* __restrict__ C,
    int M, int N, int K)
{
    __shared__ bf16 sA[2][128 * 32];
    __shared__ bf16 sB[2][128 * 32];
    const int tid  = threadIdx.x;
    const int lane = tid & 63;
    const int wave = tid >> 6;
    const int quad = lane >> 4;
    const int l15  = lane & 15;
    const int wm = (wave >> 1) * 64;
    const int wn = (wave & 1) * 64;
    const int m0 = blockIdx.y * 128;
    const int n0 = blockIdx.x * 128;

    const f32x4 fzero = {0.f, 0.f, 0.f, 0.f};
    f32x4 acc[4][4];
    #pragma unroll
    for (int i = 0; i < 4; i++)
        #pragma unroll
        for (int j = 0; j < 4; j++) acc[i][j] = fzero;

    float bv[4];
    #pragma unroll
    for (int nc = 0; nc < 4; nc++) bv[nc] = bias[n0 + wn + nc * 16 + l15];

    const int rA = lane >> 2;
    const int cAsw = ((lane & 3) ^ ((lane >> 3) & 3)) * 8;
    const int gsw = (l15 >> 1) & 3;

    GSTAGE(0, 0);
    __syncthreads();
    int buf = 0;
    for (int k0 = 0; k0 < K - 32; k0 += 32, buf ^= 1) {
        GSTAGE(k0 + 32, buf ^ 1);
        __builtin_amdgcn_sched_barrier(0);
        GCOMPUTE(buf);
        __syncthreads();
    }
    GCOMPUTE(buf);

#undef GSTAGE
#undef GCOMPUTE

    #pragma unroll
    for (int mc = 0; mc < 4; mc++) {
        #pragma unroll
        for (int reg = 0; reg < 4; reg++) {
            int row = m0 + wm + mc * 16 + quad * 4 + reg;
            size_t base = (size_t)row * N + n0 + wn;
            #pragma unroll
            for (int nc = 0; nc < 4; nc++)
                C[base + nc * 16 + l15] = acc[mc][nc][reg] + bv[nc];
        }
    }
}

// =====================================================================
// V transpose: QKVp[b][n][2048 + h*64 + d] -> Vt[b*16+h][d][n]
// =====================================================================
__global__ __launch_bounds__(256) void vtrans_kernel(
    const bf16* __restrict__ QKVp, bf16* __restrict__ Vt)
{
    __shared__ bf16 tile[64][65];
    const int bid = blockIdx.x;
    const int bh = bid >> 5;
    const int nt = bid & 31;
    const int b = bh >> 4, h = bh & 15;
    const int tid = threadIdx.x;

    #pragma unroll
    for (int i = 0; i < 16; i++) {
        int idx = i * 256 + tid;
        int rl = idx >> 6, cl = idx & 63;
        tile[rl][cl] = QKVp[(size_t)(b * 2048 + nt * 64 + rl) * 3072 + 2048 + h * 64 + cl];
    }
    __syncthreads();
    #pragma unroll
    for (int i = 0; i < 16; i++) {
        int idx = i * 256 + tid;
        int rl = idx >> 6, cl = idx & 63;
        Vt[((size_t)bh * 64 + rl) * 2048 + nt * 64 + cl] = tile[cl][rl];
    }
}

// =====================================================================
// Flash attention, P-in-registers, 64 q-rows per wave (4 Q-groups).
// (unchanged from Round 3 — dropped out of the top-5)
// =====================================================================
__global__ __launch_bounds__(128, 2) void attn_kernel(
    const bf16* __restrict__ QKV, const bf16* __restrict__ Vt,
    bf16* __restrict__ Opre)
{
    __shared__ bf16 sK[2][64 * 64];      // [key][d], swizzled, double-buffered
    __shared__ bf16 sV[2][64 * 64];      // [d][key], swizzled, double-buffered

    const int tid  = threadIdx.x;
    const int lane = tid & 63;
    const int w    = tid >> 6;            // 0..1
    const int quad = lane >> 4;
    const int l15  = lane & 15;
    // XCD-chunked swizzle: grid=1024=8*128 (bijective). XCD x owns heads
    // x*8..x*8+7 -> 8 * 512KB K/V = 4MB = one XCD L2.
    const int bid = (blockIdx.x & 7) * 128 + (blockIdx.x >> 3);
    const int bh = bid >> 4;        // 0..63
    const int qt = bid & 15;
    const int b = bh >> 4, h = bh & 15;
    const int q0 = qt * 128;

    // Q fragments as B-operand [n=q][k=d], four 16-row groups (Q pre-scaled)
    bf16x8 qF[4][2];
    #pragma unroll
    for (int g = 0; g < 4; g++) {
        size_t qrow = (size_t)(b * 2048 + q0 + w * 64 + g * 16 + l15) * 3072 + h * 64;
        qF[g][0] = *(const bf16x8*)&QKV[qrow + quad * 8];
        qF[g][1] = *(const bf16x8*)&QKV[qrow + 32 + quad * 8];
    }

    const f32x4 fzero = {0.f, 0.f, 0.f, 0.f};
    const bf16 one = (bf16)1.0f;
    const bf16x8 ones = {one, one, one, one, one, one, one, one};
    f32x4 ps[4] = {fzero, fzero, fzero, fzero};
    f32x4 o[4][4];
    #pragma unroll
    for (int g = 0; g < 4; g++)
        #pragma unroll
        for (int mt = 0; mt < 4; mt++) o[g][mt] = fzero;

    // staging: 128 threads, 64 rows x 8 granules, 4 rows/thread (stride 16)
    const int srow = tid >> 3, sseg = tid & 7;
    const size_t kbase = (size_t)(b * 2048) * 3072 + 1024 + h * 64;
    const size_t vbase = (size_t)bh * 64 * 2048;
    // swizzled granule for staging writes (p-invariant: +16 rows keeps
    // row&3 and (row>>3)&1 unchanged)
    const int sgsw = sseg ^ ((srow & 3) | (((srow >> 3) & 1) << 2));

    // swizzle factors for compute reads (row-dependent parts are l15-only)
    const int swk = (l15 & 3) | (((l15 >> 2) & 1) << 2);  // for S^T K-rows
    const int swv = (l15 & 3) | (((l15 >> 3) & 1) << 2);  // for V rows mt*16+l15

    bf16x8 stK[4], stV[4];    // in-flight staging regs (next tile)

#define ISSUE(KEY0)                                                               \
    _Pragma("unroll")                                                             \
    for (int p = 0; p < 4; p++) {                                                 \
        int row = srow + p * 16;                                                  \
        stK[p] = *(const bf16x8*)&QKV[kbase + (size_t)((KEY0) + row) * 3072 + sseg * 8]; \
        stV[p] = *(const bf16x8*)&Vt[vbase + (size_t)row * 2048 + (KEY0) + sseg * 8];    \
    }

#define COMMIT(BUF)                                                               \
    _Pragma("unroll")                                                             \
    for (int p = 0; p < 4; p++) {                                                 \
        int row = srow + p * 16;                                                  \
        *(bf16x8*)&sK[BUF][row * 64 + sgsw * 8] = stK[p];                         \
        *(bf16x8*)&sV[BUF][row * 64 + sgsw * 8] = stV[p];                         \
    }

    auto compute_tile = [&](const bf16* sKc, const bf16* sVc) {
        // S^T tiles c=0..3, keys permuted; K frags shared across all 4 q-groups.
        bf16x8 pB[4][2];
        #pragma unroll
        for (int c = 0; c < 4; c++) {
            int kr = ((l15 >> 2) << 3) + ((c & 1) << 2) + (l15 & 3) + ((c >> 1) << 5);
            bf16x8 kA0 = *(const bf16x8*)&sKc[kr * 64 + ((quad ^ swk) * 8)];
            bf16x8 kA1 = *(const bf16x8*)&sKc[kr * 64 + (((4 + quad) ^ swk) * 8)];
            #pragma unroll
            for (int g = 0; g < 4; g++) {
                __builtin_amdgcn_s_setprio(1);
                f32x4 st = mfma16(kA0, qF[g][0], fzero);
                st = mfma16(kA1, qF[g][1], st);
                __builtin_amdgcn_s_setprio(0);
                #pragma unroll
                for (int r = 0; r < 4; r++) {
                    float p = __builtin_amdgcn_exp2f(st[r]);
                    pB[g][c >> 1][(c & 1) * 4 + r] = (bf16)p;
                }
            }
        }
        // psum on the matrix pipe: colsum over this tile's 64 keys
        __builtin_amdgcn_s_setprio(1);
        #pragma unroll
        for (int g = 0; g < 4; g++) {
            ps[g] = mfma16(ones, pB[g][0], ps[g]);
            ps[g] = mfma16(ones, pB[g][1], ps[g]);
        }
        __builtin_amdgcn_s_setprio(0);
        // O^T += V^T . P : V frags shared across all 4 q-groups
        #pragma unroll
        for (int mt = 0; mt < 4; mt++) {
            int vr = mt * 16 + l15;
            bf16x8 vA0 = *(const bf16x8*)&sVc[vr * 64 + ((quad ^ swv) * 8)];
            bf16x8 vA1 = *(const bf16x8*)&sVc[vr * 64 + (((4 + quad) ^ swv) * 8)];
            __builtin_amdgcn_s_setprio(1);
            #pragma unroll
            for (int g = 0; g < 4; g++) {
                o[g][mt] = mfma16(vA0, pB[g][0], o[g][mt]);
                o[g][mt] = mfma16(vA1, pB[g][1], o[g][mt]);
            }
            __builtin_amdgcn_s_setprio(0);
        }
    };

    // ---- prologue: stage tile 0 into buffer 0 ----
    ISSUE(0);
    COMMIT(0);
    __syncthreads();

    // ---- main loop: issue t+1 early, compute t, commit t+1, barrier ----
    for (int t = 0; t < 31; t++) {
        ISSUE((t + 1) * 64);
        __builtin_amdgcn_sched_barrier(0);   // pin loads above compute
        compute_tile(sK[t & 1], sV[t & 1]);
        COMMIT((t + 1) & 1);                 // vmcnt wait covered by compute
        __syncthreads();
    }
    compute_tile(sK[1], sV[1]);              // tile 31 (odd -> buf1)

#undef ISSUE
#undef COMMIT

    // psum is complete per-lane (MFMA reduced over all keys); all ps regs equal
    #pragma unroll
    for (int g = 0; g < 4; g++) {
        float inv = 1.0f / ps[g][0];
        size_t obase = (size_t)(b * 2048 + q0 + w * 64 + g * 16 + l15) * 1024 + h * 64;
        #pragma unroll
        for (int mt = 0; mt < 4; mt++) {
            bf16x4 ov = {(bf16)(o[g][mt][0] * inv), (bf16)(o[g][mt][1] * inv),
                         (bf16)(o[g][mt][2] * inv), (bf16)(o[g][mt][3] * inv)};
            *(bf16x4*)&Opre[obase + mt * 16 + quad * 4] = ov;
        }
    }
}

// =====================================================================
extern "C" void kernel_launch(void* const* d_in, const int* in_sizes, int n_in,
                              void* d_out, int out_size, void* d_ws, size_t ws_size,
                              hipStream_t stream)
{
    const float* x  = (const float*)d_in[0];
    const float* Wq = (const float*)d_in[1];
    const float* bq = (const float*)d_in[2];
    const float* Wk = (const float*)d_in[3];
    const float* bk = (const float*)d_in[4];
    const float* Wv = (const float*)d_in[5];
    const float* bv = (const float*)d_in[6];
    const float* Wo = (const float*)d_in[7];
    const float* bo = (const float*)d_in[8];
    float* out = (float*)d_out;

    bf16* WTqkv = (bf16*)d_ws;                         // 3072*1024 bf16
    bf16* WTo   = WTqkv + (size_t)3072 * 1024;         // 1024*1024 bf16
    float* bcat = (float*)(WTo + (size_t)1024 * 1024); // 3072 f32 (pad 4096)
    bf16* QKVp  = (bf16*)(bcat + 4096);                // 8192*3072 bf16
    bf16* Vt    = QKVp + (size_t)8192 * 3072;          // 64*64*2048 bf16
    bf16* Apre  = Vt + (size_t)64 * 64 * 2048;         // 8192*1024 bf16
    bf16* xb    = Apre;   // alias: x-as-bf16 lives here until attn overwrites
    (void)ws_size; (void)n_in; (void)in_sizes; (void)out_size;

    xcvt_kernel<<<4096, 256, 0, stream>>>(x, xb);
    wtrans_kernel<<<1024, 256, 0, stream>>>(Wq, Wk, Wv, Wo, WTqkv, WTo);
    biascat_kernel<<<12, 256, 0, stream>>>(bq, bk, bv, bcat);
    gemm_bf16_kernel<<<dim3(24, 64), 256, 0, stream>>>(xb, WTqkv, bcat, QKVp, 8192, 3072, 1024, 1);
    vtrans_kernel<<<2048, 256, 0, stream>>>(QKVp, Vt);
    attn_kernel<<<1024, 128, 0, stream>>>(QKVp, Vt, Apre);
    gemm_bf16_f32out_kernel<<<dim3(8, 64), 256, 0, stream>>>(Apre, WTo, bo, out, 8192, 1024, 1024);
}

// Round 5
// 269.032 us; speedup vs baseline: 1.1145x; 1.0301x over previous
//
#include <hip/hip_runtime.h>

typedef __bf16 bf16;
typedef __attribute__((ext_vector_type(8))) __bf16 bf16x8;
typedef __attribute__((ext_vector_type(4))) __bf16 bf16x4;
typedef __attribute__((ext_vector_type(4))) float f32x4;

static __device__ __forceinline__ f32x4 mfma16(bf16x8 a, bf16x8 b, f32x4 c) {
    return __builtin_amdgcn_mfma_f32_16x16x32_bf16(a, b, c, 0, 0, 0);
}

// async global->LDS, 16B per lane; lds base must be wave-uniform
static __device__ __forceinline__ void gll16(const bf16* g, bf16* l) {
    __builtin_amdgcn_global_load_lds(
        (const __attribute__((address_space(1))) unsigned int*)g,
        (__attribute__((address_space(3))) unsigned int*)l, 16, 0, 0);
}

// =====================================================================
// Fused prep: xcvt (blocks 0..4095) | wtrans (4096..5119) | biascat (5120..5131)
// One launch instead of three (saves 2 launch gaps; bodies unchanged).
// =====================================================================
__global__ __launch_bounds__(256) void prep_kernel(
    const float* __restrict__ x, bf16* __restrict__ xb,
    const float* __restrict__ Wq, const float* __restrict__ Wk,
    const float* __restrict__ Wv, const float* __restrict__ Wo,
    bf16* __restrict__ WTqkv, bf16* __restrict__ WTo,
    const float* __restrict__ bq, const float* __restrict__ bk,
    const float* __restrict__ bv, float* __restrict__ bcat)
{
    __shared__ bf16 tile[64][65];
    const int bid = blockIdx.x;
    const int tid = threadIdx.x;

    if (bid < 4096) {
        // ---- x fp32 -> bf16
        size_t i = ((size_t)bid * 256 + tid) * 8;
        float4 a0 = *(const float4*)&x[i];
        float4 a1 = *(const float4*)&x[i + 4];
        bf16x8 v = {(bf16)a0.x, (bf16)a0.y, (bf16)a0.z, (bf16)a0.w,
                    (bf16)a1.x, (bf16)a1.y, (bf16)a1.z, (bf16)a1.w};
        *(bf16x8*)&xb[i] = v;
    } else if (bid < 5120) {
        // ---- weight transpose + convert: W[k][n] -> WT[n][k] bf16
        const int wb = bid - 4096;
        const int mi = wb >> 8;
        const int t  = wb & 255;
        const int tr = t >> 4;
        const int tc = t & 15;
        const float* src = (mi == 0) ? Wq : (mi == 1) ? Wk : (mi == 2) ? Wv : Wo;
        bf16* dst = (mi < 3) ? (WTqkv + (size_t)mi * 1024 * 1024) : WTo;

        #pragma unroll
        for (int i = 0; i < 16; i++) {
            int idx = i * 256 + tid;
            int rl = idx >> 6, cl = idx & 63;
            tile[rl][cl] = (bf16)src[(size_t)(tr * 64 + rl) * 1024 + tc * 64 + cl];
        }
        __syncthreads();
        #pragma unroll
        for (int i = 0; i < 16; i++) {
            int idx = i * 256 + tid;
            int rl = idx >> 6, cl = idx & 63;
            dst[(size_t)(tc * 64 + rl) * 1024 + tr * 64 + cl] = tile[cl][rl];
        }
    } else {
        // ---- bias concat (fp32): [b_q | b_k | b_v] -> 3072 floats
        int i = (bid - 5120) * 256 + tid;
        if (i < 1024) bcat[i] = bq[i];
        else if (i < 2048) bcat[i] = bk[i - 1024];
        else if (i < 3072) bcat[i] = bv[i - 2048];
    }
}

// =====================================================================
// m97-style GEMM + T2 swizzle + 2-phase dbuf (Round 4, unchanged).
// C = A @ BT^T + bias, bf16 out; cols<1024 scaled by QSCALE if scaleQ.
// =====================================================================
#define QSCALE 0.18033688011112043f   // 0.125 * log2(e)
__global__ __launch_bounds__(256) void gemm_bf16_kernel(
    const bf16* __restrict__ A, const bf16* __restrict__ BT,
    const float* __restrict__ bias, bf16* __restrict__ C,
    int M, int N, int K, int scaleQ)
{
    __shared__ bf16 sA[2][128 * 32];
    __shared__ bf16 sB[2][128 * 32];
    const int tid  = threadIdx.x;
    const int lane = tid & 63;
    const int wave = tid >> 6;
    const int quad = lane >> 4;
    const int l15  = lane & 15;
    const int wm = (wave >> 1) * 64;
    const int wn = (wave & 1) * 64;
    const int m0 = blockIdx.y * 128;
    const int n0 = blockIdx.x * 128;

    const f32x4 fzero = {0.f, 0.f, 0.f, 0.f};
    f32x4 acc[4][4];
    #pragma unroll
    for (int i = 0; i < 4; i++)
        #pragma unroll
        for (int j = 0; j < 4; j++) acc[i][j] = fzero;

    float bv[4];
    #pragma unroll
    for (int nc = 0; nc < 4; nc++) bv[nc] = bias[n0 + wn + nc * 16 + l15];

    const int rA = lane >> 2;
    const int cAsw = ((lane & 3) ^ ((lane >> 3) & 3)) * 8;   // pre-swizzled src col
    const int gsw = (l15 >> 1) & 3;                          // read granule swizzle

#define GSTAGE(K0, BUF)                                                           \
    _Pragma("unroll")                                                             \
    for (int p = 0; p < 2; p++) {                                                 \
        int r16 = (wave * 2 + p) * 16;                                            \
        gll16(&A[(size_t)(m0 + r16 + rA) * K + (K0) + cAsw], &sA[BUF][r16 * 32]); \
        gll16(&BT[(size_t)(n0 + r16 + rA) * K + (K0) + cAsw], &sB[BUF][r16 * 32]);\
    }

#define GCOMPUTE(BUF)                                                             \
    {                                                                             \
        bf16x8 aF[4], bF[4];                                                      \
        _Pragma("unroll")                                                         \
        for (int mc = 0; mc < 4; mc++)                                            \
            aF[mc] = *(const bf16x8*)&sA[BUF][(wm + mc * 16 + l15) * 32 + ((quad ^ gsw) * 8)]; \
        _Pragma("unroll")                                                         \
        for (int nc = 0; nc < 4; nc++)                                            \
            bF[nc] = *(const bf16x8*)&sB[BUF][(wn + nc * 16 + l15) * 32 + ((quad ^ gsw) * 8)]; \
        _Pragma("unroll")                                                         \
        for (int mc = 0; mc < 4; mc++)                                            \
            _Pragma("unroll")                                                     \
            for (int nc = 0; nc < 4; nc++)                                        \
                acc[mc][nc] = mfma16(aF[mc], bF[nc], acc[mc][nc]);                \
    }

    GSTAGE(0, 0);
    __syncthreads();
    int buf = 0;
    for (int k0 = 0; k0 < K - 32; k0 += 32, buf ^= 1) {
        GSTAGE(k0 + 32, buf ^ 1);
        __builtin_amdgcn_sched_barrier(0);   // keep stage issue above compute
        GCOMPUTE(buf);
        __syncthreads();                     // vmcnt drain: one phase after issue
    }
    GCOMPUTE(buf);                           // last tile

    const float sc = (scaleQ && n0 < 1024) ? QSCALE : 1.0f;
    #pragma unroll
    for (int mc = 0; mc < 4; mc++) {
        #pragma unroll
        for (int reg = 0; reg < 4; reg++) {
            int row = m0 + wm + mc * 16 + quad * 4 + reg;
            size_t base = (size_t)row * N + n0 + wn;
            #pragma unroll
            for (int nc = 0; nc < 4; nc++)
                C[base + nc * 16 + l15] = (bf16)((acc[mc][nc][reg] + bv[nc]) * sc);
        }
    }
}

// Same structure, fp32 output (final projection -> d_out)
__global__ __launch_bounds__(256) void gemm_bf16_f32out_kernel(
    const bf16* __restrict__ A, const bf16* __restrict__ BT,
    const float* __restrict__ bias, float* __restrict__ C,
    int M, int N, int K)
{
    __shared__ bf16 sA[2][128 * 32];
    __shared__ bf16 sB[2][128 * 32];
    const int tid  = threadIdx.x;
    const int lane = tid & 63;
    const int wave = tid >> 6;
    const int quad = lane >> 4;
    const int l15  = lane & 15;
    const int wm = (wave >> 1) * 64;
    const int wn = (wave & 1) * 64;
    const int m0 = blockIdx.y * 128;
    const int n0 = blockIdx.x * 128;

    const f32x4 fzero = {0.f, 0.f, 0.f, 0.f};
    f32x4 acc[4][4];
    #pragma unroll
    for (int i = 0; i < 4; i++)
        #pragma unroll
        for (int j = 0; j < 4; j++) acc[i][j] = fzero;

    float bv[4];
    #pragma unroll
    for (int nc = 0; nc < 4; nc++) bv[nc] = bias[n0 + wn + nc * 16 + l15];

    const int rA = lane >> 2;
    const int cAsw = ((lane & 3) ^ ((lane >> 3) & 3)) * 8;
    const int gsw = (l15 >> 1) & 3;

    GSTAGE(0, 0);
    __syncthreads();
    int buf = 0;
    for (int k0 = 0; k0 < K - 32; k0 += 32, buf ^= 1) {
        GSTAGE(k0 + 32, buf ^ 1);
        __builtin_amdgcn_sched_barrier(0);
        GCOMPUTE(buf);
        __syncthreads();
    }
    GCOMPUTE(buf);

#undef GSTAGE
#undef GCOMPUTE

    #pragma unroll
    for (int mc = 0; mc < 4; mc++) {
        #pragma unroll
        for (int reg = 0; reg < 4; reg++) {
            int row = m0 + wm + mc * 16 + quad * 4 + reg;
            size_t base = (size_t)row * N + n0 + wn;
            #pragma unroll
            for (int nc = 0; nc < 4; nc++)
                C[base + nc * 16 + l15] = acc[mc][nc][reg] + bv[nc];
        }
    }
}

// =====================================================================
// V transpose: QKVp[b][n][2048 + h*64 + d] -> Vt[b*16+h][d][n]
// =====================================================================
__global__ __launch_bounds__(256) void vtrans_kernel(
    const bf16* __restrict__ QKVp, bf16* __restrict__ Vt)
{
    __shared__ bf16 tile[64][65];
    const int bid = blockIdx.x;
    const int bh = bid >> 5;
    const int nt = bid & 31;
    const int b = bh >> 4, h = bh & 15;
    const int tid = threadIdx.x;

    #pragma unroll
    for (int i = 0; i < 16; i++) {
        int idx = i * 256 + tid;
        int rl = idx >> 6, cl = idx & 63;
        tile[rl][cl] = QKVp[(size_t)(b * 2048 + nt * 64 + rl) * 3072 + 2048 + h * 64 + cl];
    }
    __syncthreads();
    #pragma unroll
    for (int i = 0; i < 16; i++) {
        int idx = i * 256 + tid;
        int rl = idx >> 6, cl = idx & 63;
        Vt[((size_t)bh * 64 + rl) * 2048 + nt * 64 + cl] = tile[cl][rl];
    }
}

// =====================================================================
// Flash attention, P-in-registers, 64 q-rows per wave (4 Q-groups).
// Round-4 change: both pipes <40% busy with zero conflicts and low HBM ->
// dependency-stall bound.  The 16 s_setprio toggle pairs per tile fenced
// the scheduler into 2-MFMA regions (setprio has side effects; instrs
// don't migrate across).  Removed (one coarse pair per tile).  Tile
// restructured as a ks-split pipeline: QKT(keys 0..31) -> pB[*][0];
// then {QKT(keys 32..63) || PV-half0 + psum-half0} as independent MFMA
// streams the scheduler can interleave with the exp2 VALU stream; then
// PV-half1.  V k-slot-0 fragment reads hoisted above the second QKT.
// Everything else (swizzles, dbuf, T14 issue-early staging, XCD swizzle,
// MFMA-ones psum) unchanged.
// =====================================================================
__global__ __launch_bounds__(128, 2) void attn_kernel(
    const bf16* __restrict__ QKV, const bf16* __restrict__ Vt,
    bf16* __restrict__ Opre)
{
    __shared__ bf16 sK[2][64 * 64];      // [key][d], swizzled, double-buffered
    __shared__ bf16 sV[2][64 * 64];      // [d][key], swizzled, double-buffered

    const int tid  = threadIdx.x;
    const int lane = tid & 63;
    const int w    = tid >> 6;            // 0..1
    const int quad = lane >> 4;
    const int l15  = lane & 15;
    // XCD-chunked swizzle: grid=1024=8*128 (bijective). XCD x owns heads
    // x*8..x*8+7 -> 8 * 512KB K/V = 4MB = one XCD L2.
    const int bid = (blockIdx.x & 7) * 128 + (blockIdx.x >> 3);
    const int bh = bid >> 4;        // 0..63
    const int qt = bid & 15;
    const int b = bh >> 4, h = bh & 15;
    const int q0 = qt * 128;

    // Q fragments as B-operand [n=q][k=d], four 16-row groups (Q pre-scaled)
    bf16x8 qF[4][2];
    #pragma unroll
    for (int g = 0; g < 4; g++) {
        size_t qrow = (size_t)(b * 2048 + q0 + w * 64 + g * 16 + l15) * 3072 + h * 64;
        qF[g][0] = *(const bf16x8*)&QKV[qrow + quad * 8];
        qF[g][1] = *(const bf16x8*)&QKV[qrow + 32 + quad * 8];
    }

    const f32x4 fzero = {0.f, 0.f, 0.f, 0.f};
    const bf16 one = (bf16)1.0f;
    const bf16x8 ones = {one, one, one, one, one, one, one, one};
    f32x4 ps[4] = {fzero, fzero, fzero, fzero};
    f32x4 o[4][4];
    #pragma unroll
    for (int g = 0; g < 4; g++)
        #pragma unroll
        for (int mt = 0; mt < 4; mt++) o[g][mt] = fzero;

    // staging: 128 threads, 64 rows x 8 granules, 4 rows/thread (stride 16)
    const int srow = tid >> 3, sseg = tid & 7;
    const size_t kbase = (size_t)(b * 2048) * 3072 + 1024 + h * 64;
    const size_t vbase = (size_t)bh * 64 * 2048;
    // swizzled granule for staging writes (p-invariant: +16 rows keeps
    // row&3 and (row>>3)&1 unchanged)
    const int sgsw = sseg ^ ((srow & 3) | (((srow >> 3) & 1) << 2));

    // swizzle factors for compute reads (row-dependent parts are l15-only)
    const int swk = (l15 & 3) | (((l15 >> 2) & 1) << 2);  // for S^T K-rows
    const int swv = (l15 & 3) | (((l15 >> 3) & 1) << 2);  // for V rows mt*16+l15

    bf16x8 stK[4], stV[4];    // in-flight staging regs (next tile)

#define ISSUE(KEY0)                                                               \
    _Pragma("unroll")                                                             \
    for (int p = 0; p < 4; p++) {                                                 \
        int row = srow + p * 16;                                                  \
        stK[p] = *(const bf16x8*)&QKV[kbase + (size_t)((KEY0) + row) * 3072 + sseg * 8]; \
        stV[p] = *(const bf16x8*)&Vt[vbase + (size_t)row * 2048 + (KEY0) + sseg * 8];    \
    }

#define COMMIT(BUF)                                                               \
    _Pragma("unroll")                                                             \
    for (int p = 0; p < 4; p++) {                                                 \
        int row = srow + p * 16;                                                  \
        *(bf16x8*)&sK[BUF][row * 64 + sgsw * 8] = stK[p];                         \
        *(bf16x8*)&sV[BUF][row * 64 + sgsw * 8] = stV[p];                         \
    }

    auto compute_tile = [&](const bf16* sKc, const bf16* sVc) {
        bf16x8 pB[4][2];
        __builtin_amdgcn_s_setprio(1);
        // ---- QK^T keys 0..31 (c=0,1) -> pB[*][0]
        #pragma unroll
        for (int c = 0; c < 2; c++) {
            int kr = ((l15 >> 2) << 3) + (c << 2) + (l15 & 3);
            bf16x8 kA0 = *(const bf16x8*)&sKc[kr * 64 + ((quad ^ swk) * 8)];
            bf16x8 kA1 = *(const bf16x8*)&sKc[kr * 64 + (((4 + quad) ^ swk) * 8)];
            #pragma unroll
            for (int g = 0; g < 4; g++) {
                f32x4 st = mfma16(kA0, qF[g][0], fzero);
                st = mfma16(kA1, qF[g][1], st);
                #pragma unroll
                for (int r = 0; r < 4; r++) {
                    float p = __builtin_amdgcn_exp2f(st[r]);
                    pB[g][0][c * 4 + r] = (bf16)p;
                }
            }
        }
        // ---- V k-slot-0 fragments (for PV half 0)
        bf16x8 vA0[4];
        #pragma unroll
        for (int mt = 0; mt < 4; mt++)
            vA0[mt] = *(const bf16x8*)&sVc[(mt * 16 + l15) * 64 + ((quad ^ swv) * 8)];
        // ---- QK^T keys 32..63 (c=2,3) -> pB[*][1]   (independent of PV0)
        #pragma unroll
        for (int c = 0; c < 2; c++) {
            int kr = ((l15 >> 2) << 3) + (c << 2) + (l15 & 3) + 32;
            bf16x8 kA0 = *(const bf16x8*)&sKc[kr * 64 + ((quad ^ swk) * 8)];
            bf16x8 kA1 = *(const bf16x8*)&sKc[kr * 64 + (((4 + quad) ^ swk) * 8)];
            #pragma unroll
            for (int g = 0; g < 4; g++) {
                f32x4 st = mfma16(kA0, qF[g][0], fzero);
                st = mfma16(kA1, qF[g][1], st);
                #pragma unroll
                for (int r = 0; r < 4; r++) {
                    float p = __builtin_amdgcn_exp2f(st[r]);
                    pB[g][1][c * 4 + r] = (bf16)p;
                }
            }
        }
        // ---- PV half 0 + psum half 0 (keys 0..31; overlaps QKT above)
        #pragma unroll
        for (int g = 0; g < 4; g++) ps[g] = mfma16(ones, pB[g][0], ps[g]);
        #pragma unroll
        for (int mt = 0; mt < 4; mt++)
            #pragma unroll
            for (int g = 0; g < 4; g++)
                o[g][mt] = mfma16(vA0[mt], pB[g][0], o[g][mt]);
        // ---- PV half 1 + psum half 1 (keys 32..63)
        bf16x8 vA1[4];
        #pragma unroll
        for (int mt = 0; mt < 4; mt++)
            vA1[mt] = *(const bf16x8*)&sVc[(mt * 16 + l15) * 64 + (((4 + quad) ^ swv) * 8)];
        #pragma unroll
        for (int g = 0; g < 4; g++) ps[g] = mfma16(ones, pB[g][1], ps[g]);
        #pragma unroll
        for (int mt = 0; mt < 4; mt++)
            #pragma unroll
            for (int g = 0; g < 4; g++)
                o[g][mt] = mfma16(vA1[mt], pB[g][1], o[g][mt]);
        __builtin_amdgcn_s_setprio(0);
    };

    // ---- prologue: stage tile 0 into buffer 0 ----
    ISSUE(0);
    COMMIT(0);
    __syncthreads();

    // ---- main loop: issue t+1 early, compute t, commit t+1, barrier ----
    for (int t = 0; t < 31; t++) {
        ISSUE((t + 1) * 64);
        __builtin_amdgcn_sched_barrier(0);   // pin loads above compute
        compute_tile(sK[t & 1], sV[t & 1]);
        COMMIT((t + 1) & 1);                 // vmcnt wait covered by compute
        __syncthreads();
    }
    compute_tile(sK[1], sV[1]);              // tile 31 (odd -> buf1)

#undef ISSUE
#undef COMMIT

    // psum is complete per-lane (MFMA reduced over all keys); all ps regs equal
    #pragma unroll
    for (int g = 0; g < 4; g++) {
        float inv = 1.0f / ps[g][0];
        size_t obase = (size_t)(b * 2048 + q0 + w * 64 + g * 16 + l15) * 1024 + h * 64;
        #pragma unroll
        for (int mt = 0; mt < 4; mt++) {
            bf16x4 ov = {(bf16)(o[g][mt][0] * inv), (bf16)(o[g][mt][1] * inv),
                         (bf16)(o[g][mt][2] * inv), (bf16)(o[g][mt][3] * inv)};
            *(bf16x4*)&Opre[obase + mt * 16 + quad * 4] = ov;
        }
    }
}

// =====================================================================
extern "C" void kernel_launch(void* const* d_in, const int* in_sizes, int n_in,
                              void* d_out, int out_size, void* d_ws, size_t ws_size,
                              hipStream_t stream)
{
    const float* x  = (const float*)d_in[0];
    const float* Wq = (const float*)d_in[1];
    const float* bq = (const float*)d_in[2];
    const float* Wk = (const float*)d_in[3];
    const float* bk = (const float*)d_in[4];
    const float* Wv = (const float*)d_in[5];
    const float* bv = (const float*)d_in[6];
    const float* Wo = (const float*)d_in[7];
    const float* bo = (const float*)d_in[8];
    float* out = (float*)d_out;

    bf16* WTqkv = (bf16*)d_ws;                         // 3072*1024 bf16
    bf16* WTo   = WTqkv + (size_t)3072 * 1024;         // 1024*1024 bf16
    float* bcat = (float*)(WTo + (size_t)1024 * 1024); // 3072 f32 (pad 4096)
    bf16* QKVp  = (bf16*)(bcat + 4096);                // 8192*3072 bf16
    bf16* Vt    = QKVp + (size_t)8192 * 3072;          // 64*64*2048 bf16
    bf16* Apre  = Vt + (size_t)64 * 64 * 2048;         // 8192*1024 bf16
    bf16* xb    = Apre;   // alias: x-as-bf16 lives here until attn overwrites
    (void)ws_size; (void)n_in; (void)in_sizes; (void)out_size;

    prep_kernel<<<5132, 256, 0, stream>>>(x, xb, Wq, Wk, Wv, Wo, WTqkv, WTo,
                                          bq, bk, bv, bcat);
    gemm_bf16_kernel<<<dim3(24, 64), 256, 0, stream>>>(xb, WTqkv, bcat, QKVp, 8192, 3072, 1024, 1);
    vtrans_kernel<<<2048, 256, 0, stream>>>(QKVp, Vt);
    attn_kernel<<<1024, 128, 0, stream>>>(QKVp, Vt, Apre);
    gemm_bf16_f32out_kernel<<<dim3(8, 64), 256, 0, stream>>>(Apre, WTo, bo, out, 8192, 1024, 1024);
}

// Round 6
// 265.497 us; speedup vs baseline: 1.1293x; 1.0133x over previous
//
#include <hip/hip_runtime.h>

typedef __bf16 bf16;
typedef __attribute__((ext_vector_type(8))) __bf16 bf16x8;
typedef __attribute__((ext_vector_type(4))) __bf16 bf16x4;
typedef __attribute__((ext_vector_type(4))) float f32x4;

static __device__ __forceinline__ f32x4 mfma16(bf16x8 a, bf16x8 b, f32x4 c) {
    return __builtin_amdgcn_mfma_f32_16x16x32_bf16(a, b, c, 0, 0, 0);
}

// async global->LDS, 16B per lane; lds base must be wave-uniform
static __device__ __forceinline__ void gll16(const bf16* g, bf16* l) {
    __builtin_amdgcn_global_load_lds(
        (const __attribute__((address_space(1))) unsigned int*)g,
        (__attribute__((address_space(3))) unsigned int*)l, 16, 0, 0);
}

// =====================================================================
// Fused prep: xcvt (blocks 0..4095) | wtrans (4096..5119) | biascat (5120..5131)
// =====================================================================
__global__ __launch_bounds__(256) void prep_kernel(
    const float* __restrict__ x, bf16* __restrict__ xb,
    const float* __restrict__ Wq, const float* __restrict__ Wk,
    const float* __restrict__ Wv, const float* __restrict__ Wo,
    bf16* __restrict__ WTqkv, bf16* __restrict__ WTo,
    const float* __restrict__ bq, const float* __restrict__ bk,
    const float* __restrict__ bv, float* __restrict__ bcat)
{
    __shared__ bf16 tile[64][65];
    const int bid = blockIdx.x;
    const int tid = threadIdx.x;

    if (bid < 4096) {
        size_t i = ((size_t)bid * 256 + tid) * 8;
        float4 a0 = *(const float4*)&x[i];
        float4 a1 = *(const float4*)&x[i + 4];
        bf16x8 v = {(bf16)a0.x, (bf16)a0.y, (bf16)a0.z, (bf16)a0.w,
                    (bf16)a1.x, (bf16)a1.y, (bf16)a1.z, (bf16)a1.w};
        *(bf16x8*)&xb[i] = v;
    } else if (bid < 5120) {
        const int wb = bid - 4096;
        const int mi = wb >> 8;
        const int t  = wb & 255;
        const int tr = t >> 4;
        const int tc = t & 15;
        const float* src = (mi == 0) ? Wq : (mi == 1) ? Wk : (mi == 2) ? Wv : Wo;
        bf16* dst = (mi < 3) ? (WTqkv + (size_t)mi * 1024 * 1024) : WTo;

        #pragma unroll
        for (int i = 0; i < 16; i++) {
            int idx = i * 256 + tid;
            int rl = idx >> 6, cl = idx & 63;
            tile[rl][cl] = (bf16)src[(size_t)(tr * 64 + rl) * 1024 + tc * 64 + cl];
        }
        __syncthreads();
        #pragma unroll
        for (int i = 0; i < 16; i++) {
            int idx = i * 256 + tid;
            int rl = idx >> 6, cl = idx & 63;
            dst[(size_t)(tc * 64 + rl) * 1024 + tr * 64 + cl] = tile[cl][rl];
        }
    } else {
        int i = (bid - 5120) * 256 + tid;
        if (i < 1024) bcat[i] = bq[i];
        else if (i < 2048) bcat[i] = bk[i - 1024];
        else if (i < 3072) bcat[i] = bv[i - 2048];
    }
}

// =====================================================================
// m97-style GEMM + T2 swizzle + 2-phase dbuf (unchanged from Round 4).
// =====================================================================
#define QSCALE 0.18033688011112043f   // 0.125 * log2(e)
__global__ __launch_bounds__(256) void gemm_bf16_kernel(
    const bf16* __restrict__ A, const bf16* __restrict__ BT,
    const float* __restrict__ bias, bf16* __restrict__ C,
    int M, int N, int K, int scaleQ)
{
    __shared__ bf16 sA[2][128 * 32];
    __shared__ bf16 sB[2][128 * 32];
    const int tid  = threadIdx.x;
    const int lane = tid & 63;
    const int wave = tid >> 6;
    const int quad = lane >> 4;
    const int l15  = lane & 15;
    const int wm = (wave >> 1) * 64;
    const int wn = (wave & 1) * 64;
    const int m0 = blockIdx.y * 128;
    const int n0 = blockIdx.x * 128;

    const f32x4 fzero = {0.f, 0.f, 0.f, 0.f};
    f32x4 acc[4][4];
    #pragma unroll
    for (int i = 0; i < 4; i++)
        #pragma unroll
        for (int j = 0; j < 4; j++) acc[i][j] = fzero;

    float bv[4];
    #pragma unroll
    for (int nc = 0; nc < 4; nc++) bv[nc] = bias[n0 + wn + nc * 16 + l15];

    const int rA = lane >> 2;
    const int cAsw = ((lane & 3) ^ ((lane >> 3) & 3)) * 8;   // pre-swizzled src col
    const int gsw = (l15 >> 1) & 3;                          // read granule swizzle

#define GSTAGE(K0, BUF)                                                           \
    _Pragma("unroll")                                                             \
    for (int p = 0; p < 2; p++) {                                                 \
        int r16 = (wave * 2 + p) * 16;                                            \
        gll16(&A[(size_t)(m0 + r16 + rA) * K + (K0) + cAsw], &sA[BUF][r16 * 32]); \
        gll16(&BT[(size_t)(n0 + r16 + rA) * K + (K0) + cAsw], &sB[BUF][r16 * 32]);\
    }

#define GCOMPUTE(BUF)                                                             \
    {                                                                             \
        bf16x8 aF[4], bF[4];                                                      \
        _Pragma("unroll")                                                         \
        for (int mc = 0; mc < 4; mc++)                                            \
            aF[mc] = *(const bf16x8*)&sA[BUF][(wm + mc * 16 + l15) * 32 + ((quad ^ gsw) * 8)]; \
        _Pragma("unroll")                                                         \
        for (int nc = 0; nc < 4; nc++)                                            \
            bF[nc] = *(const bf16x8*)&sB[BUF][(wn + nc * 16 + l15) * 32 + ((quad ^ gsw) * 8)]; \
        _Pragma("unroll")                                                         \
        for (int mc = 0; mc < 4; mc++)                                            \
            _Pragma("unroll")                                                     \
            for (int nc = 0; nc < 4; nc++)                                        \
                acc[mc][nc] = mfma16(aF[mc], bF[nc], acc[mc][nc]);                \
    }

    GSTAGE(0, 0);
    __syncthreads();
    int buf = 0;
    for (int k0 = 0; k0 < K - 32; k0 += 32, buf ^= 1) {
        GSTAGE(k0 + 32, buf ^ 1);
        __builtin_amdgcn_sched_barrier(0);
        GCOMPUTE(buf);
        __syncthreads();
    }
    GCOMPUTE(buf);

    const float sc = (scaleQ && n0 < 1024) ? QSCALE : 1.0f;
    #pragma unroll
    for (int mc = 0; mc < 4; mc++) {
        #pragma unroll
        for (int reg = 0; reg < 4; reg++) {
            int row = m0 + wm + mc * 16 + quad * 4 + reg;
            size_t base = (size_t)row * N + n0 + wn;
            #pragma unroll
            for (int nc = 0; nc < 4; nc++)
                C[base + nc * 16 + l15] = (bf16)((acc[mc][nc][reg] + bv[nc]) * sc);
        }
    }
}

// Same structure, fp32 output (final projection -> d_out)
__global__ __launch_bounds__(256) void gemm_bf16_f32out_kernel(
    const bf16* __restrict__ A, const bf16* __restrict__ BT,
    const float* __restrict__ bias, float* __restrict__ C,
    int M, int N, int K)
{
    __shared__ bf16 sA[2][128 * 32];
    __shared__ bf16 sB[2][128 * 32];
    const int tid  = threadIdx.x;
    const int lane = tid & 63;
    const int wave = tid >> 6;
    const int quad = lane >> 4;
    const int l15  = lane & 15;
    const int wm = (wave >> 1) * 64;
    const int wn = (wave & 1) * 64;
    const int m0 = blockIdx.y * 128;
    const int n0 = blockIdx.x * 128;

    const f32x4 fzero = {0.f, 0.f, 0.f, 0.f};
    f32x4 acc[4][4];
    #pragma unroll
    for (int i = 0; i < 4; i++)
        #pragma unroll
        for (int j = 0; j < 4; j++) acc[i][j] = fzero;

    float bv[4];
    #pragma unroll
    for (int nc = 0; nc < 4; nc++) bv[nc] = bias[n0 + wn + nc * 16 + l15];

    const int rA = lane >> 2;
    const int cAsw = ((lane & 3) ^ ((lane >> 3) & 3)) * 8;
    const int gsw = (l15 >> 1) & 3;

    GSTAGE(0, 0);
    __syncthreads();
    int buf = 0;
    for (int k0 = 0; k0 < K - 32; k0 += 32, buf ^= 1) {
        GSTAGE(k0 + 32, buf ^ 1);
        __builtin_amdgcn_sched_barrier(0);
        GCOMPUTE(buf);
        __syncthreads();
    }
    GCOMPUTE(buf);

#undef GSTAGE
#undef GCOMPUTE

    #pragma unroll
    for (int mc = 0; mc < 4; mc++) {
        #pragma unroll
        for (int reg = 0; reg < 4; reg++) {
            int row = m0 + wm + mc * 16 + quad * 4 + reg;
            size_t base = (size_t)row * N + n0 + wn;
            #pragma unroll
            for (int nc = 0; nc < 4; nc++)
                C[base + nc * 16 + l15] = acc[mc][nc][reg] + bv[nc];
        }
    }
}

// =====================================================================
// V transpose: QKVp[b][n][2048 + h*64 + d] -> Vt[b*16+h][d][n]
// =====================================================================
__global__ __launch_bounds__(256) void vtrans_kernel(
    const bf16* __restrict__ QKVp, bf16* __restrict__ Vt)
{
    __shared__ bf16 tile[64][65];
    const int bid = blockIdx.x;
    const int bh = bid >> 5;
    const int nt = bid & 31;
    const int b = bh >> 4, h = bh & 15;
    const int tid = threadIdx.x;

    #pragma unroll
    for (int i = 0; i < 16; i++) {
        int idx = i * 256 + tid;
        int rl = idx >> 6, cl = idx & 63;
        tile[rl][cl] = QKVp[(size_t)(b * 2048 + nt * 64 + rl) * 3072 + 2048 + h * 64 + cl];
    }
    __syncthreads();
    #pragma unroll
    for (int i = 0; i < 16; i++) {
        int idx = i * 256 + tid;
        int rl = idx >> 6, cl = idx & 63;
        Vt[((size_t)bh * 64 + rl) * 2048 + nt * 64 + cl] = tile[cl][rl];
    }
}

// =====================================================================
// Flash attention, 64 q-rows per wave, T15 cross-tile double-pipeline.
// Round-5 change: per-tile serial chain QKT->exp2->pack->PV left the
// MFMA pipe at 44% with VALU at 42% (exp2 is 1/4-rate: ~512cyc/tile).
// Now two P-states (pA/pB, static-named): each body runs PV(tile t)
// [40 dependency-free MFMAs] concurrently with QKT(t+1)->exp2->pack,
// giving the scheduler an independent MFMA stream to overlap the exp2.
// Staging switched to global_load_lds with PRE-SWIZZLED global source
// (m173: LDS dest linear/wave-uniform, XOR involution on src granule)
// -> no staging regs, no ds_writes, 1 barrier/tile.
// Schedule (even t): VREAD V(t) | barrier | STAGE(t+2->buf[t&1]) |
//   QKT(t+1 from buf[~t&1])->pB  ||  PV(t) with pA,vA
// =====================================================================
__global__ __launch_bounds__(128, 2) void attn_kernel(
    const bf16* __restrict__ QKV, const bf16* __restrict__ Vt,
    bf16* __restrict__ Opre)
{
    __shared__ bf16 sK[2][64 * 64];      // [key][d], swizzled, double-buffered
    __shared__ bf16 sV[2][64 * 64];      // [d][key], swizzled, double-buffered

    const int tid  = threadIdx.x;
    const int lane = tid & 63;
    const int w    = tid >> 6;            // 0..1
    const int quad = lane >> 4;
    const int l15  = lane & 15;
    // XCD-chunked swizzle: grid=1024=8*128 (bijective).
    const int bid = (blockIdx.x & 7) * 128 + (blockIdx.x >> 3);
    const int bh = bid >> 4;        // 0..63
    const int qt = bid & 15;
    const int b = bh >> 4, h = bh & 15;
    const int q0 = qt * 128;

    // Q fragments as B-operand [n=q][k=d], four 16-row groups (Q pre-scaled)
    bf16x8 qF[4][2];
    #pragma unroll
    for (int g = 0; g < 4; g++) {
        size_t qrow = (size_t)(b * 2048 + q0 + w * 64 + g * 16 + l15) * 3072 + h * 64;
        qF[g][0] = *(const bf16x8*)&QKV[qrow + quad * 8];
        qF[g][1] = *(const bf16x8*)&QKV[qrow + 32 + quad * 8];
    }

    const f32x4 fzero = {0.f, 0.f, 0.f, 0.f};
    const bf16 one = (bf16)1.0f;
    const bf16x8 ones = {one, one, one, one, one, one, one, one};
    f32x4 ps[4] = {fzero, fzero, fzero, fzero};
    f32x4 o[4][4];
    #pragma unroll
    for (int g = 0; g < 4; g++)
        #pragma unroll
        for (int mt = 0; mt < 4; mt++) o[g][mt] = fzero;

    // staging geometry: 128 threads, 64 rows x 8 granules, 4 rows/thread
    const int srow = tid >> 3, sseg = tid & 7;
    const size_t kbase = (size_t)(b * 2048) * 3072 + 1024 + h * 64;
    const size_t vbase = (size_t)bh * 64 * 2048;
    // src-granule swizzle (involution; p-invariant under row+=16)
    const int sgsw = sseg ^ ((srow & 3) | (((srow >> 3) & 1) << 2));

    // compute-read swizzle factors (l15-only parts)
    const int swk = (l15 & 3) | (((l15 >> 2) & 1) << 2);  // S^T K-rows
    const int swv = (l15 & 3) | (((l15 >> 3) & 1) << 2);  // V rows mt*16+l15

    bf16x8 pAr[4][2], pBr[4][2];   // two in-flight P states (static-indexed)
    bf16x8 vA[4][2];               // V fragments of the PV tile

// global_load_lds staging, pre-swizzled source, linear wave-uniform dest
#define STAGE(KEY0, BUF)                                                          \
    _Pragma("unroll")                                                             \
    for (int p = 0; p < 4; p++) {                                                 \
        int row = srow + p * 16;                                                  \
        gll16(&QKV[kbase + (size_t)((KEY0) + row) * 3072 + sgsw * 8],             \
              &sK[BUF][(w * 8 + p * 16) * 64]);                                   \
        gll16(&Vt[vbase + (size_t)row * 2048 + (KEY0) + sgsw * 8],                \
              &sV[BUF][(w * 8 + p * 16) * 64]);                                   \
    }

#define VREAD(SV)                                                                 \
    _Pragma("unroll")                                                             \
    for (int mt = 0; mt < 4; mt++) {                                              \
        vA[mt][0] = *(const bf16x8*)&(SV)[(mt * 16 + l15) * 64 + ((quad ^ swv) * 8)];       \
        vA[mt][1] = *(const bf16x8*)&(SV)[(mt * 16 + l15) * 64 + (((4 + quad) ^ swv) * 8)]; \
    }

#define QKT(PB, SK)                                                               \
    _Pragma("unroll")                                                             \
    for (int ch = 0; ch < 2; ch++) {                                              \
        _Pragma("unroll")                                                         \
        for (int c = 0; c < 2; c++) {                                             \
            int kr = ((l15 >> 2) << 3) + (c << 2) + (l15 & 3) + ch * 32;          \
            bf16x8 kA0 = *(const bf16x8*)&(SK)[kr * 64 + ((quad ^ swk) * 8)];     \
            bf16x8 kA1 = *(const bf16x8*)&(SK)[kr * 64 + (((4 + quad) ^ swk) * 8)];\
            _Pragma("unroll")                                                     \
            for (int g = 0; g < 4; g++) {                                         \
                f32x4 st = mfma16(kA0, qF[g][0], fzero);                          \
                st = mfma16(kA1, qF[g][1], st);                                   \
                _Pragma("unroll")                                                 \
                for (int r = 0; r < 4; r++)                                       \
                    PB[g][ch][c * 4 + r] = (bf16)__builtin_amdgcn_exp2f(st[r]);   \
            }                                                                     \
        }                                                                         \
    }

#define PVACC(PA)                                                                 \
    _Pragma("unroll")                                                             \
    for (int g = 0; g < 4; g++) {                                                 \
        ps[g] = mfma16(ones, PA[g][0], ps[g]);                                    \
        ps[g] = mfma16(ones, PA[g][1], ps[g]);                                    \
    }                                                                             \
    _Pragma("unroll")                                                             \
    for (int mt = 0; mt < 4; mt++)                                                \
        _Pragma("unroll")                                                         \
        for (int g = 0; g < 4; g++) {                                             \
            o[g][mt] = mfma16(vA[mt][0], PA[g][0], o[g][mt]);                     \
            o[g][mt] = mfma16(vA[mt][1], PA[g][1], o[g][mt]);                     \
        }

    // ---- prologue: stage tile0 -> buf0; P(0) -> pAr; stage tile1 -> buf1
    STAGE(0, 0);
    __syncthreads();
    QKT(pAr, sK[0]);
    STAGE(64, 1);

    // ---- main: 15 double-bodies (t=0..29), then t=30, then epilogue t=31
    for (int tt = 0; tt < 15; tt++) {
        const int t = tt * 2;
        // even body: PV(t) w/ pAr+vA, QKT(t+1)->pBr, stage(t+2)->buf0
        VREAD(sV[0]);
        __syncthreads();
        STAGE((t + 2) * 64, 0);
        __builtin_amdgcn_sched_barrier(0);
        __builtin_amdgcn_s_setprio(1);
        QKT(pBr, sK[1]);
        PVACC(pAr);
        __builtin_amdgcn_s_setprio(0);
        // odd body: PV(t+1) w/ pBr+vA, QKT(t+2)->pAr, stage(t+3)->buf1
        VREAD(sV[1]);
        __syncthreads();
        STAGE((t + 3) * 64, 1);
        __builtin_amdgcn_sched_barrier(0);
        __builtin_amdgcn_s_setprio(1);
        QKT(pAr, sK[0]);
        PVACC(pBr);
        __builtin_amdgcn_s_setprio(0);
    }
    // t=30 (even): PV(30) w/ pAr, QKT(31)->pBr, no stage
    VREAD(sV[0]);
    __syncthreads();
    __builtin_amdgcn_s_setprio(1);
    QKT(pBr, sK[1]);
    PVACC(pAr);
    __builtin_amdgcn_s_setprio(0);
    // epilogue: PV(31) w/ pBr; sV[1] final (no writers after t=30's barrier)
    VREAD(sV[1]);
    PVACC(pBr);

#undef STAGE
#undef VREAD
#undef QKT
#undef PVACC

    // psum complete per-lane (MFMA-reduced over all keys); all ps regs equal
    #pragma unroll
    for (int g = 0; g < 4; g++) {
        float inv = 1.0f / ps[g][0];
        size_t obase = (size_t)(b * 2048 + q0 + w * 64 + g * 16 + l15) * 1024 + h * 64;
        #pragma unroll
        for (int mt = 0; mt < 4; mt++) {
            bf16x4 ov = {(bf16)(o[g][mt][0] * inv), (bf16)(o[g][mt][1] * inv),
                         (bf16)(o[g][mt][2] * inv), (bf16)(o[g][mt][3] * inv)};
            *(bf16x4*)&Opre[obase + mt * 16 + quad * 4] = ov;
        }
    }
}

// =====================================================================
extern "C" void kernel_launch(void* const* d_in, const int* in_sizes, int n_in,
                              void* d_out, int out_size, void* d_ws, size_t ws_size,
                              hipStream_t stream)
{
    const float* x  = (const float*)d_in[0];
    const float* Wq = (const float*)d_in[1];
    const float* bq = (const float*)d_in[2];
    const float* Wk = (const float*)d_in[3];
    const float* bk = (const float*)d_in[4];
    const float* Wv = (const float*)d_in[5];
    const float* bv = (const float*)d_in[6];
    const float* Wo = (const float*)d_in[7];
    const float* bo = (const float*)d_in[8];
    float* out = (float*)d_out;

    bf16* WTqkv = (bf16*)d_ws;                         // 3072*1024 bf16
    bf16* WTo   = WTqkv + (size_t)3072 * 1024;         // 1024*1024 bf16
    float* bcat = (float*)(WTo + (size_t)1024 * 1024); // 3072 f32 (pad 4096)
    bf16* QKVp  = (bf16*)(bcat + 4096);                // 8192*3072 bf16
    bf16* Vt    = QKVp + (size_t)8192 * 3072;          // 64*64*2048 bf16
    bf16* Apre  = Vt + (size_t)64 * 64 * 2048;         // 8192*1024 bf16
    bf16* xb    = Apre;   // alias: x-as-bf16 lives here until attn overwrites
    (void)ws_size; (void)n_in; (void)in_sizes; (void)out_size;

    prep_kernel<<<5132, 256, 0, stream>>>(x, xb, Wq, Wk, Wv, Wo, WTqkv, WTo,
                                          bq, bk, bv, bcat);
    gemm_bf16_kernel<<<dim3(24, 64), 256, 0, stream>>>(xb, WTqkv, bcat, QKVp, 8192, 3072, 1024, 1);
    vtrans_kernel<<<2048, 256, 0, stream>>>(QKVp, Vt);
    attn_kernel<<<1024, 128, 0, stream>>>(QKVp, Vt, Apre);
    gemm_bf16_f32out_kernel<<<dim3(8, 64), 256, 0, stream>>>(Apre, WTo, bo, out, 8192, 1024, 1024);
}